// Round 8
// baseline (172.983 us; speedup 1.0000x reference)
//
#include <hip/hip_runtime.h>
#include <hip/hip_bf16.h>

#define SLEN 2048
#define HDIM 2048
#define NHEAD 32
#define KVHEAD 8
#define HEADD 64
#define NTOT 3104
#define NPAD 3200

typedef short bh8 __attribute__((ext_vector_type(8)));
typedef float f32x4 __attribute__((ext_vector_type(4)));

// 0.125 * log2(e): folded into Q so QK^T MFMA emits log2-domain scores
#define QSCALE 0.1803368801111204f

__device__ __forceinline__ unsigned short f2bf(float f) {
    union { float f; unsigned int u; } v; v.f = f;
    unsigned int u = v.u;
    return (unsigned short)((u + 0x7fffu + ((u >> 16) & 1u)) >> 16);
}

// HW packed f32->bf16 (RNE), 1 instruction instead of ~10 bit-ops
__device__ __forceinline__ unsigned int cvtpk_bf16(float lo, float hi) {
    unsigned int r;
    asm("v_cvt_pk_bf16_f32 %0, %1, %2" : "=v"(r) : "v"(lo), "v"(hi));
    return r;
}

__device__ __forceinline__ void gl_lds16(const unsigned short* g, unsigned short* l) {
    __builtin_amdgcn_global_load_lds(
        (const __attribute__((address_space(1))) unsigned int*)g,
        (__attribute__((address_space(3))) unsigned int*)l, 16, 0, 0);
}

// ---------------- cast hidden fp32 -> bf16 ----------------
__global__ void cast_x_k(const float* __restrict__ src, unsigned short* __restrict__ dst, int n) {
    int i = blockIdx.x * blockDim.x + threadIdx.x;
    int base = i * 4;
    if (base < n) {
        float4 f = *(const float4*)(src + base);
        ushort4 o;
        o.x = f2bf(f.x); o.y = f2bf(f.y); o.z = f2bf(f.z); o.w = f2bf(f.w);
        *(ushort4*)(dst + base) = o;
    }
}

// ---------------- pack [Wq|gates|Wk|Wv] transposed -> bf16 (NPAD x HDIM) ----------------
__global__ void pack_wt_k(const float* __restrict__ Wq, const float* __restrict__ Wk,
                          const float* __restrict__ Wv, unsigned short* __restrict__ Wt) {
    __shared__ float tile[32][33];
    int n0 = blockIdx.x * 32, k0 = blockIdx.y * 32;
    int t = threadIdx.x;
    for (int i = 0; i < 4; i++) {
        int idx = i * 256 + t;
        int kr = idx >> 5, nc = idx & 31;
        int n = n0 + nc, k = k0 + kr;
        float val = 0.f;
        if (n < 2048)       { int h = n >> 6, d = n & 63; val = Wq[(size_t)k * 2080 + (h >> 2) * 260 + (h & 3) * 64 + d]; }
        else if (n < 2080)  { int h = n - 2048;           val = Wq[(size_t)k * 2080 + (h >> 2) * 260 + 256 + (h & 3)]; }
        else if (n < 2592)  { val = Wk[(size_t)k * 512 + (n - 2080)]; }
        else if (n < 3104)  { val = Wv[(size_t)k * 512 + (n - 2592)]; }
        tile[kr][nc] = val;
    }
    __syncthreads();
    for (int i = 0; i < 4; i++) {
        int idx = i * 256 + t;
        int nr = idx >> 5, kc = idx & 31;
        Wt[(size_t)(n0 + nr) * HDIM + (k0 + kc)] = f2bf(tile[kc][nr]);
    }
}

// ---------------- transpose-cast Wo -> bf16 (2048 x 2048) ----------------
__global__ void pack_wot_k(const float* __restrict__ Wo, unsigned short* __restrict__ Wt) {
    __shared__ float tile[32][33];
    int n0 = blockIdx.x * 32, k0 = blockIdx.y * 32;
    int t = threadIdx.x;
    for (int i = 0; i < 4; i++) {
        int idx = i * 256 + t;
        int kr = idx >> 5, nc = idx & 31;
        tile[kr][nc] = Wo[(size_t)(k0 + kr) * 2048 + (n0 + nc)];
    }
    __syncthreads();
    for (int i = 0; i < 4; i++) {
        int idx = i * 256 + t;
        int nr = idx >> 5, kc = idx & 31;
        Wt[(size_t)(n0 + nr) * 2048 + (k0 + kc)] = f2bf(tile[kc][nr]);
    }
}

// ---------------- QKV NT GEMM: 128x128 tile, split-K x2 (R8) ----------------
// R7 showed 64x128 plateaus at ~490 TF with NO pipe >20% busy: per-wave intensity too
// low (8 MFMA/barrier, 21.8 FLOP per LDS byte). 128^2 tile: 16 MFMA/barrier, 32.8 FLOP/B.
// Natural grid is only 400 blocks (1.56/CU trap, m102) -> split K=2048 into 2x1024 ->
// 800 blocks at 3.1/CU writing two f32 partials; consumers sum them.
// 2-buf LDS (32KB -> 5/CU cap), stage-after-barrier (WAR-safe with 2 buffers; stage has
// a full 16-MFMA body of issue lead before its vmcnt(0)), unroll-2 static indices.
__global__ __launch_bounds__(256) void gemm_nt128_k(const unsigned short* __restrict__ A,
                                                    const unsigned short* __restrict__ Bt,
                                                    float* __restrict__ C0,
                                                    float* __restrict__ C1) {
    const int K = 2048, ldc = NPAD;
    __shared__ unsigned short As[2][128 * 32];
    __shared__ unsigned short Bs[2][128 * 32];
    int d = blockIdx.x;                    // 800
    int swz = (d & 7) * 100 + (d >> 3);    // XCD swizzle, bijective (800 % 8 == 0)
    int half = swz >= 400;
    int tile = swz - half * 400;
    int m0 = (tile & 15) * 128, n0 = (tile >> 4) * 128;   // 16 x 25 tiles
    float* C = half ? C1 : C0;
    int t = threadIdx.x;
    int w = t >> 6, l = t & 63;
    int wm = (w >> 1) * 64, wn = (w & 1) * 64;
    int lrow = l & 15, lc = l >> 4;
    int rsw = (lrow >> 1) & 3;
    int scol = ((l & 3) ^ ((l >> 3) & 3)) * 8;   // pre-swizzled source chunk
    int srowA = w * 32 + (l >> 2);

    f32x4 acc[4][4];
    #pragma unroll
    for (int i = 0; i < 4; i++)
        #pragma unroll
        for (int j = 0; j < 4; j++)
            acc[i][j] = {0.f, 0.f, 0.f, 0.f};

    const unsigned short* ga = &A[(size_t)(m0 + srowA) * K + half * 1024 + scol];
    const unsigned short* gb = &Bt[(size_t)(n0 + srowA) * K + half * 1024 + scol];

#define STAGE128(s, b) do { \
        const unsigned short* a0 = ga + (size_t)(s) * 32; \
        const unsigned short* b0 = gb + (size_t)(s) * 32; \
        gl_lds16(a0,                  &As[b][(w * 2 + 0) * 512]); \
        gl_lds16(a0 + 16 * (size_t)K, &As[b][(w * 2 + 1) * 512]); \
        gl_lds16(b0,                  &Bs[b][(w * 2 + 0) * 512]); \
        gl_lds16(b0 + 16 * (size_t)K, &Bs[b][(w * 2 + 1) * 512]); \
    } while (0)

#define GBODY128(rb) do { \
        bh8 af[4], bb[4]; \
        _Pragma("unroll") \
        for (int i = 0; i < 4; i++) \
            af[i] = *(const bh8*)(&As[rb][(wm + i * 16 + lrow) * 32 + ((lc ^ rsw) * 8)]); \
        _Pragma("unroll") \
        for (int j = 0; j < 4; j++) \
            bb[j] = *(const bh8*)(&Bs[rb][(wn + j * 16 + lrow) * 32 + ((lc ^ rsw) * 8)]); \
        _Pragma("unroll") \
        for (int i = 0; i < 4; i++) \
            _Pragma("unroll") \
            for (int j = 0; j < 4; j++) \
                acc[i][j] = __builtin_amdgcn_mfma_f32_16x16x32_bf16(af[i], bb[j], acc[i][j], 0, 0, 0); \
    } while (0)

#define WB0 asm volatile("s_waitcnt vmcnt(0)\n\ts_barrier" ::: "memory")

    // prologue: stage tile 0 -> buf0 (4 loads/wave)
    STAGE128(0, 0);
    // 32 K-steps of 32. Per step: [drain my stage-s + barrier][stage s+1 (other buf,
    // WAR-safe: all waves passed the barrier after reading it last at s-1)][compute s].
    for (int sb = 0; sb < 32; sb += 2) {
        WB0;
        STAGE128(sb + 1, 1);
        GBODY128(0);
        WB0;
        if (sb + 2 < 32) STAGE128(sb + 2, 0);
        GBODY128(1);
    }
#undef WB0
#undef STAGE128
#undef GBODY128
    int col = l & 15, rbase = (l >> 4) * 4;
    for (int i = 0; i < 4; i++)
        for (int j = 0; j < 4; j++)
            #pragma unroll
            for (int r = 0; r < 4; r++)
                C[(size_t)(m0 + wm + i * 16 + rbase + r) * ldc + (n0 + wn + j * 16 + col)] = acc[i][j][r];
}

// ---------------- out-proj NT GEMM, 64x128 tile (R7 structure, unchanged) ----------------
__global__ __launch_bounds__(256) void gemm_nt64_k(const unsigned short* __restrict__ A,
                                                   const unsigned short* __restrict__ Bt,
                                                   float* __restrict__ C,
                                                   int ldc, int mtiles) {
    const int K = 2048;
    __shared__ unsigned short As[3][64 * 32];
    __shared__ unsigned short Bs[3][128 * 32];
    int d = blockIdx.x;
    int nwg = gridDim.x;
    int cpx = nwg >> 3;
    int swz = (d & 7) * cpx + (d >> 3);
    int m0 = (swz % mtiles) * 64, n0 = (swz / mtiles) * 128;
    int t = threadIdx.x;
    int w = t >> 6, l = t & 63;
    int wm = (w >> 1) * 32, wn = (w & 1) * 64;
    int lrow = l & 15, lc = l >> 4;
    int rsw = (lrow >> 1) & 3;
    int scol = ((l & 3) ^ ((l >> 3) & 3)) * 8;

    f32x4 acc[2][4];
    #pragma unroll
    for (int i = 0; i < 2; i++)
        #pragma unroll
        for (int j = 0; j < 4; j++)
            acc[i][j] = {0.f, 0.f, 0.f, 0.f};

    const unsigned short* ga = &A[(size_t)(m0 + w * 16 + (l >> 2)) * K + scol];
    const unsigned short* gb = &Bt[(size_t)(n0 + w * 32 + (l >> 2)) * K + scol];

#define STAGE_NT64(s, b) do { \
        gl_lds16(ga + (size_t)(s) * 32,                  &As[b][w * 512]); \
        gl_lds16(gb + (size_t)(s) * 32,                  &Bs[b][(w * 2 + 0) * 512]); \
        gl_lds16(gb + (size_t)(s) * 32 + 16 * (size_t)K, &Bs[b][(w * 2 + 1) * 512]); \
    } while (0)

#define GBODY(rb) do { \
        bh8 af[2], bb[4]; \
        _Pragma("unroll") \
        for (int i = 0; i < 2; i++) \
            af[i] = *(const bh8*)(&As[rb][(wm + i * 16 + lrow) * 32 + ((lc ^ rsw) * 8)]); \
        _Pragma("unroll") \
        for (int j = 0; j < 4; j++) \
            bb[j] = *(const bh8*)(&Bs[rb][(wn + j * 16 + lrow) * 32 + ((lc ^ rsw) * 8)]); \
        _Pragma("unroll") \
        for (int i = 0; i < 2; i++) \
            _Pragma("unroll") \
            for (int j = 0; j < 4; j++) \
                acc[i][j] = __builtin_amdgcn_mfma_f32_16x16x32_bf16(af[i], bb[j], acc[i][j], 0, 0, 0); \
    } while (0)

#define WB3 asm volatile("s_waitcnt vmcnt(3)\n\ts_barrier" ::: "memory")

    STAGE_NT64(0, 0);
    STAGE_NT64(1, 1);
    for (int sb = 0; sb < 60; sb += 3) {
        WB3;
        STAGE_NT64(sb + 2, 2);
        GBODY(0);
        WB3;
        STAGE_NT64(sb + 3, 0);
        GBODY(1);
        WB3;
        STAGE_NT64(sb + 4, 1);
        GBODY(2);
    }
    WB3;
    STAGE_NT64(62, 2);
    GBODY(0);
    WB3;
    STAGE_NT64(63, 0);
    GBODY(1);
    WB3;
    GBODY(2);
    asm volatile("s_waitcnt vmcnt(0)\n\ts_barrier" ::: "memory");
    GBODY(0);
#undef WB3
#undef STAGE_NT64
#undef GBODY
    int col = l & 15, rbase = (l >> 4) * 4;
    for (int i = 0; i < 2; i++)
        for (int j = 0; j < 4; j++)
            #pragma unroll
            for (int r = 0; r < 4; r++)
                C[(size_t)(m0 + wm + i * 16 + rbase + r) * ldc + (n0 + wn + j * 16 + col)] = acc[i][j][r];
}

// ---------------- RMSNorm + RoPE for Q,K (sums split-K partials) ----------------
__global__ void norm_rope_k(const float* __restrict__ QKVG, const float* __restrict__ QKVG1,
                            unsigned short* __restrict__ Qr, unsigned short* __restrict__ Kr,
                            const float* __restrict__ g_q, const float* __restrict__ g_k) {
    int wid = blockIdx.x * (blockDim.x >> 6) + (threadIdx.x >> 6);
    int lane = threadIdx.x & 63;
    int type, s, hh;
    if (wid < SLEN * NHEAD) { type = 0; s = wid >> 5; hh = wid & 31; }
    else                    { int r = wid - SLEN * NHEAD; type = 1; s = r >> 3; hh = r & 7; }
    int col = (type == 0) ? hh * 64 + lane : 2080 + hh * 64 + lane;
    size_t idx = (size_t)s * NPAD + col;
    float x = QKVG[idx] + QKVG1[idx];
    float sq = x * x;
    #pragma unroll
    for (int off = 32; off; off >>= 1) sq += __shfl_xor(sq, off);
    float inv = rsqrtf(sq * (1.f / 64.f) + 1e-6f);
    float g = (type == 0 ? g_q : g_k)[lane];
    float xn = x * inv * g;
    float xp = __shfl_xor(xn, 32);
    float xr = (lane < 32) ? -xp : xp;
    int i = lane & 31;
    float invf = __expf(-(float)i * (0.03125f * 13.815510557964274f));
    float ang = (float)s * invf;
    float c = cosf(ang), sn = sinf(ang);
    float r = xn * c + xr * sn;
    if (type == 0) Qr[((size_t)hh * SLEN + s) * 64 + lane] = f2bf(r * QSCALE);
    else           Kr[((size_t)hh * SLEN + s) * 64 + lane] = f2bf(r);
}

// ---------------- V transpose + key-permute (sums split-K partials) ----------------
__global__ void vt_k(const float* __restrict__ QKVG, const float* __restrict__ QKVG1,
                     unsigned short* __restrict__ Vt) {
    __shared__ float tile[64][65];
    int s0 = blockIdx.x * 64, hh = blockIdx.y;
    int t = threadIdx.x;
    #pragma unroll
    for (int i = 0; i < 4; i++) {
        int idx = i * 256 + t;
        int sr = idx >> 4, c4 = (idx & 15) * 4;
        size_t off = (size_t)(s0 + sr) * NPAD + 2592 + hh * 64 + c4;
        float4 f = *(const float4*)(&QKVG[off]);
        float4 f1 = *(const float4*)(&QKVG1[off]);
        tile[sr][c4] = f.x + f1.x; tile[sr][c4 + 1] = f.y + f1.y;
        tile[sr][c4 + 2] = f.z + f1.z; tile[sr][c4 + 3] = f.w + f1.w;
    }
    __syncthreads();
    #pragma unroll
    for (int i = 0; i < 4; i++) {
        int idx = i * 256 + t;
        int dr = idx >> 4, c4 = (idx & 15) * 4;
        int hb = c4 >> 5, f = (c4 >> 4) & 1, g = (c4 >> 2) & 3;
        int p = (hb * 4 + g) * 8 + f * 4;
        ushort4 o;
        o.x = f2bf(tile[c4][dr]); o.y = f2bf(tile[c4 + 1][dr]);
        o.z = f2bf(tile[c4 + 2][dr]); o.w = f2bf(tile[c4 + 3][dr]);
        *(ushort4*)(&Vt[((size_t)hh * 64 + dr) * SLEN + s0 + p]) = o;
    }
}

// ---------------- sigmoid(gate) (sums split-K partials) ----------------
__global__ void gate_sig_k(const float* __restrict__ QKVG, const float* __restrict__ QKVG1,
                           float* __restrict__ gate) {
    int i = blockIdx.x * 256 + threadIdx.x;
    int s = i >> 5, h = i & 31;
    size_t idx = (size_t)s * NPAD + 2048 + h;
    float x = QKVG[idx] + QKVG1[idx];
    gate[i] = 1.f / (1.f + __expf(-x));
}

// ---------------- causal GQA flash attention + gate (R4 structure, unchanged) ----------------
__global__ __launch_bounds__(256) void attn_k(const unsigned short* __restrict__ Qr,
                                              const unsigned short* __restrict__ Kr,
                                              const unsigned short* __restrict__ Vt,
                                              const float* __restrict__ gate,
                                              unsigned short* __restrict__ attn) {
    __shared__ unsigned short Kls[3][64 * 64];
    __shared__ unsigned short Vls[3][64 * 64];
    int d = blockIdx.x;
    int kvh = d & 7;
    int h = kvh * 4 + ((d >> 3) & 3);
    int qt = 31 - (d >> 5);          // big-first: span-32 blocks dispatch first
    int t = threadIdx.x, w = t >> 6, l = t & 63;
    int ql = l & 15, g = l >> 4;
    const float NEGINF = -__builtin_inff();

    const unsigned short* Kh = Kr + (size_t)kvh * SLEN * 64;
    const unsigned short* Vh = Vt + (size_t)kvh * 64 * SLEN;
    const unsigned short* Qh = Qr + (size_t)h * SLEN * 64;
    int lk = g * 8;
    int r8 = l >> 3, c8 = l & 7;
    int cs = 8 * (c8 ^ r8);          // pre-swizzled source col (shorts)
    int R0 = w * 16, R1 = w * 16 + 8;
    int rdswz = (ql & 7) << 4;       // read-side XOR swizzle (bytes)

    int q0 = qt * 64;
    int qrow = q0 + w * 16 + ql;

    bh8 qa0 = *(const bh8*)(Qh + (size_t)qrow * 64 + lk);
    bh8 qa1 = *(const bh8*)(Qh + (size_t)qrow * 64 + 32 + lk);

    f32x4 o[4];
    #pragma unroll
    for (int i = 0; i < 4; i++) o[i] = {0.f, 0.f, 0.f, 0.f};
    float m2 = NEGINF, lsum = 0.f;

    int ntiles = qt + 1;
    {
        gl_lds16(&Kh[(size_t)(0 + R0 + r8) * 64 + cs], &Kls[0][R0 * 64]);
        gl_lds16(&Kh[(size_t)(0 + R1 + r8) * 64 + cs], &Kls[0][R1 * 64]);
        gl_lds16(&Vh[(size_t)(R0 + r8) * SLEN + 0 + cs], &Vls[0][R0 * 64]);
        gl_lds16(&Vh[(size_t)(R1 + r8) * SLEN + 0 + cs], &Vls[0][R1 * 64]);
    }
    if (ntiles > 1) {
        gl_lds16(&Kh[(size_t)(64 + R0 + r8) * 64 + cs], &Kls[1][R0 * 64]);
        gl_lds16(&Kh[(size_t)(64 + R1 + r8) * 64 + cs], &Kls[1][R1 * 64]);
        gl_lds16(&Vh[(size_t)(R0 + r8) * SLEN + 64 + cs], &Vls[1][R0 * 64]);
        gl_lds16(&Vh[(size_t)(R1 + r8) * SLEN + 64 + cs], &Vls[1][R1 * 64]);
    }
    int rd = 0, wr = 2;

    for (int ti = 0; ti < ntiles; ti++) {
        if (ti + 1 < ntiles) asm volatile("s_waitcnt vmcnt(4)\n\ts_barrier" ::: "memory");
        else                 asm volatile("s_waitcnt vmcnt(0)\n\ts_barrier" ::: "memory");
        if (ti + 2 < ntiles) {
            int kv1 = (ti + 2) * 64;
            gl_lds16(&Kh[(size_t)(kv1 + R0 + r8) * 64 + cs], &Kls[wr][R0 * 64]);
            gl_lds16(&Kh[(size_t)(kv1 + R1 + r8) * 64 + cs], &Kls[wr][R1 * 64]);
            gl_lds16(&Vh[(size_t)(R0 + r8) * SLEN + kv1 + cs], &Vls[wr][R0 * 64]);
            gl_lds16(&Vh[(size_t)(R1 + r8) * SLEN + kv1 + cs], &Vls[wr][R1 * 64]);
        }
        const unsigned short* Kb = &Kls[rd][0];
        const unsigned short* Vb = &Vls[rd][0];
        int kv0 = ti * 64;
        f32x4 sct[4];
        __builtin_amdgcn_s_setprio(1);
        #pragma unroll
        for (int nt = 0; nt < 4; nt++) {
            int rb = (nt * 16 + ql) * 128;
            bh8 kb0 = *(const bh8*)(&Kb[(rb + ((g * 16) ^ rdswz)) >> 1]);
            bh8 kb1 = *(const bh8*)(&Kb[(rb + ((64 + g * 16) ^ rdswz)) >> 1]);
            f32x4 a = {0.f, 0.f, 0.f, 0.f};
            a = __builtin_amdgcn_mfma_f32_16x16x32_bf16(kb0, qa0, a, 0, 0, 0);
            a = __builtin_amdgcn_mfma_f32_16x16x32_bf16(kb1, qa1, a, 0, 0, 0);
            sct[nt] = a;
        }
        __builtin_amdgcn_s_setprio(0);
        if (ti == qt) {
            #pragma unroll
            for (int nt = 0; nt < 4; nt++)
                #pragma unroll
                for (int j = 0; j < 4; j++) {
                    int key = kv0 + nt * 16 + 4 * g + j;
                    if (key > qrow) sct[nt][j] = NEGINF;
                }
        }
        float mt0 = fmaxf(fmaxf(sct[0][0], sct[0][1]), fmaxf(sct[0][2], sct[0][3]));
        float mt1 = fmaxf(fmaxf(sct[1][0], sct[1][1]), fmaxf(sct[1][2], sct[1][3]));
        float mt2 = fmaxf(fmaxf(sct[2][0], sct[2][1]), fmaxf(sct[2][2], sct[2][3]));
        float mt3 = fmaxf(fmaxf(sct[3][0], sct[3][1]), fmaxf(sct[3][2], sct[3][3]));
        float mt = fmaxf(fmaxf(mt0, mt1), fmaxf(mt2, mt3));
        mt = fmaxf(mt, __shfl_xor(mt, 16));
        mt = fmaxf(mt, __shfl_xor(mt, 32));
        if (!__all(mt - m2 <= 8.f)) {
            float mnew = fmaxf(m2, mt);
            float resc = __builtin_amdgcn_exp2f(m2 - mnew);
            m2 = mnew;
            lsum *= resc;
            float rf[4];
            #pragma unroll
            for (int j = 0; j < 4; j++) rf[j] = __shfl(resc, 4 * g + j);
            #pragma unroll
            for (int nt = 0; nt < 4; nt++) {
                f32x4 oo = o[nt];
                #pragma unroll
                for (int j = 0; j < 4; j++) oo[j] *= rf[j];
                o[nt] = oo;
            }
        }
        float ps = 0.f;
        #pragma unroll
        for (int nt = 0; nt < 4; nt++)
            #pragma unroll
            for (int j = 0; j < 4; j++) {
                float p = __builtin_amdgcn_exp2f(sct[nt][j] - m2);
                sct[nt][j] = p;
                ps += p;
            }
        ps += __shfl_xor(ps, 16);
        ps += __shfl_xor(ps, 32);
        lsum += ps;
        union { unsigned int u[4]; bh8 v; } pa0, pa1;
        pa0.u[0] = cvtpk_bf16(sct[0][0], sct[0][1]);
        pa0.u[1] = cvtpk_bf16(sct[0][2], sct[0][3]);
        pa0.u[2] = cvtpk_bf16(sct[1][0], sct[1][1]);
        pa0.u[3] = cvtpk_bf16(sct[1][2], sct[1][3]);
        pa1.u[0] = cvtpk_bf16(sct[2][0], sct[2][1]);
        pa1.u[1] = cvtpk_bf16(sct[2][2], sct[2][3]);
        pa1.u[2] = cvtpk_bf16(sct[3][0], sct[3][1]);
        pa1.u[3] = cvtpk_bf16(sct[3][2], sct[3][3]);
        __builtin_amdgcn_s_setprio(1);
        #pragma unroll
        for (int nt = 0; nt < 4; nt++) {
            int rb = (nt * 16 + ql) * 128;
            bh8 vb0 = *(const bh8*)(&Vb[(rb + ((g * 16) ^ rdswz)) >> 1]);
            bh8 vb1 = *(const bh8*)(&Vb[(rb + ((64 + g * 16) ^ rdswz)) >> 1]);
            o[nt] = __builtin_amdgcn_mfma_f32_16x16x32_bf16(pa0.v, vb0, o[nt], 0, 0, 0);
            o[nt] = __builtin_amdgcn_mfma_f32_16x16x32_bf16(pa1.v, vb1, o[nt], 0, 0, 0);
        }
        __builtin_amdgcn_s_setprio(0);
        rd = (rd == 2) ? 0 : rd + 1;
        wr = (wr == 2) ? 0 : wr + 1;
    }

    float gf[4];
    #pragma unroll
    for (int j = 0; j < 4; j++) {
        float ls = __shfl(lsum, 4 * g + j);
        int row = q0 + w * 16 + 4 * g + j;
        gf[j] = gate[row * 32 + h] / ls;
    }
    #pragma unroll
    for (int j = 0; j < 4; j++) {
        int row = q0 + w * 16 + 4 * g + j;
        #pragma unroll
        for (int nt = 0; nt < 4; nt++)
            attn[(size_t)row * 2048 + h * 64 + nt * 16 + ql] = f2bf(o[nt][j] * gf[j]);
    }
}

extern "C" void kernel_launch(void* const* d_in, const int* in_sizes, int n_in,
                              void* d_out, int out_size, void* d_ws, size_t ws_size,
                              hipStream_t stream) {
    const float* hidden = (const float*)d_in[0];
    const float* Wq = (const float*)d_in[1];
    const float* Wk = (const float*)d_in[2];
    const float* Wv = (const float*)d_in[3];
    const float* Wo = (const float*)d_in[4];
    const float* gq = (const float*)d_in[5];
    const float* gk = (const float*)d_in[6];
    float* out = (float*)d_out;
    char* ws = (char*)d_ws;

    unsigned short* X     = (unsigned short*)(ws + 0);         //  8388608 B
    unsigned short* Wt    = (unsigned short*)(ws + 8388608);   // 13107200 B
    float*          QKVG  = (float*)(ws + 21495808);           // 26214400 B
    unsigned short* Qr    = (unsigned short*)(ws + 47710208);  //  8388608 B
    unsigned short* Kr    = (unsigned short*)(ws + 56098816);  //  2097152 B
    unsigned short* Vt    = (unsigned short*)(ws + 58195968);  //  2097152 B
    float*          gate  = (float*)(ws + 60293120);           //   262144 B
    unsigned short* attn  = (unsigned short*)(ws + 60555264);  //  8388608 B
    unsigned short* Wot   = (unsigned short*)(ws + 68943872);  //  8388608 B
    float*          QKVG1 = (float*)(ws + 77332480);           // 26214400 B (split-K partial)

    cast_x_k<<<dim3(4096), dim3(256), 0, stream>>>(hidden, X, SLEN * HDIM);
    pack_wt_k<<<dim3(100, 64), dim3(256), 0, stream>>>(Wq, Wk, Wv, Wt);
    pack_wot_k<<<dim3(64, 64), dim3(256), 0, stream>>>(Wo, Wot);
    gemm_nt128_k<<<dim3(800), dim3(256), 0, stream>>>(X, Wt, QKVG, QKVG1);
    norm_rope_k<<<dim3(20480), dim3(256), 0, stream>>>(QKVG, QKVG1, Qr, Kr, gq, gk);
    vt_k<<<dim3(32, 8), dim3(256), 0, stream>>>(QKVG, QKVG1, Vt);
    gate_sig_k<<<dim3(256), dim3(256), 0, stream>>>(QKVG, QKVG1, gate);
    attn_k<<<dim3(1024), dim3(256), 0, stream>>>(Qr, Kr, Vt, gate, attn);
    gemm_nt64_k<<<dim3(512), dim3(256), 0, stream>>>(attn, Wot, out, 2048, 32);
}

// Round 9
// 170.739 us; speedup vs baseline: 1.0131x; 1.0131x over previous
//
#include <hip/hip_runtime.h>
#include <hip/hip_bf16.h>

#define SLEN 2048
#define HDIM 2048
#define NHEAD 32
#define KVHEAD 8
#define HEADD 64
#define NTOT 3104
#define NPAD 3200

typedef short bh8 __attribute__((ext_vector_type(8)));
typedef float f32x4 __attribute__((ext_vector_type(4)));

// 0.125 * log2(e): folded into Q so QK^T MFMA emits log2-domain scores
#define QSCALE 0.1803368801111204f

__device__ __forceinline__ unsigned short f2bf(float f) {
    union { float f; unsigned int u; } v; v.f = f;
    unsigned int u = v.u;
    return (unsigned short)((u + 0x7fffu + ((u >> 16) & 1u)) >> 16);
}

// HW packed f32->bf16 (RNE), 1 instruction instead of ~10 bit-ops
__device__ __forceinline__ unsigned int cvtpk_bf16(float lo, float hi) {
    unsigned int r;
    asm("v_cvt_pk_bf16_f32 %0, %1, %2" : "=v"(r) : "v"(lo), "v"(hi));
    return r;
}

__device__ __forceinline__ void gl_lds16(const unsigned short* g, unsigned short* l) {
    __builtin_amdgcn_global_load_lds(
        (const __attribute__((address_space(1))) unsigned int*)g,
        (__attribute__((address_space(3))) unsigned int*)l, 16, 0, 0);
}

// ---------------- cast hidden fp32 -> bf16 ----------------
__global__ void cast_x_k(const float* __restrict__ src, unsigned short* __restrict__ dst, int n) {
    int i = blockIdx.x * blockDim.x + threadIdx.x;
    int base = i * 4;
    if (base < n) {
        float4 f = *(const float4*)(src + base);
        ushort4 o;
        o.x = f2bf(f.x); o.y = f2bf(f.y); o.z = f2bf(f.z); o.w = f2bf(f.w);
        *(ushort4*)(dst + base) = o;
    }
}

// ---------------- pack [Wq|gates|Wk|Wv] transposed -> bf16 (NPAD x HDIM) ----------------
__global__ void pack_wt_k(const float* __restrict__ Wq, const float* __restrict__ Wk,
                          const float* __restrict__ Wv, unsigned short* __restrict__ Wt) {
    __shared__ float tile[32][33];
    int n0 = blockIdx.x * 32, k0 = blockIdx.y * 32;
    int t = threadIdx.x;
    for (int i = 0; i < 4; i++) {
        int idx = i * 256 + t;
        int kr = idx >> 5, nc = idx & 31;
        int n = n0 + nc, k = k0 + kr;
        float val = 0.f;
        if (n < 2048)       { int h = n >> 6, d = n & 63; val = Wq[(size_t)k * 2080 + (h >> 2) * 260 + (h & 3) * 64 + d]; }
        else if (n < 2080)  { int h = n - 2048;           val = Wq[(size_t)k * 2080 + (h >> 2) * 260 + 256 + (h & 3)]; }
        else if (n < 2592)  { val = Wk[(size_t)k * 512 + (n - 2080)]; }
        else if (n < 3104)  { val = Wv[(size_t)k * 512 + (n - 2592)]; }
        tile[kr][nc] = val;
    }
    __syncthreads();
    for (int i = 0; i < 4; i++) {
        int idx = i * 256 + t;
        int nr = idx >> 5, kc = idx & 31;
        Wt[(size_t)(n0 + nr) * HDIM + (k0 + kc)] = f2bf(tile[kc][nr]);
    }
}

// ---------------- transpose-cast Wo -> bf16 (2048 x 2048) ----------------
__global__ void pack_wot_k(const float* __restrict__ Wo, unsigned short* __restrict__ Wt) {
    __shared__ float tile[32][33];
    int n0 = blockIdx.x * 32, k0 = blockIdx.y * 32;
    int t = threadIdx.x;
    for (int i = 0; i < 4; i++) {
        int idx = i * 256 + t;
        int kr = idx >> 5, nc = idx & 31;
        tile[kr][nc] = Wo[(size_t)(k0 + kr) * 2048 + (n0 + nc)];
    }
    __syncthreads();
    for (int i = 0; i < 4; i++) {
        int idx = i * 256 + t;
        int nr = idx >> 5, kc = idx & 31;
        Wt[(size_t)(n0 + nr) * 2048 + (k0 + kc)] = f2bf(tile[kc][nr]);
    }
}

// ---------------- QKV NT GEMM: 128x128 tile, split-K x2 (R9) ----------------
// R9 = R8's geometry (128^2 intensity, split-K x2 -> 800 blocks ~3/CU) + the two
// proven pipeline ingredients R8 lacked: 3 LDS buffers with COUNTED vmcnt(4)
// (R8's 2-buf forced vmcnt(0)/step = ~400cy drain stall, QKV 55->61 regression)
// and unroll-3 static buffer indices (R6/R7: VALUBusy 32->13%).
// LDS 48KB -> 3 blocks/CU cap (grid is 3.1/CU, fits). 4 loads/wave/step:
// loop-top has 8 outstanding -> vmcnt(4) drains my stage-s, keeps s+1 in flight.
__global__ __launch_bounds__(256) void gemm_nt128_k(const unsigned short* __restrict__ A,
                                                    const unsigned short* __restrict__ Bt,
                                                    float* __restrict__ C0,
                                                    float* __restrict__ C1) {
    const int K = 2048, ldc = NPAD;
    __shared__ unsigned short As[3][128 * 32];
    __shared__ unsigned short Bs[3][128 * 32];
    int d = blockIdx.x;                    // 800
    int swz = (d & 7) * 100 + (d >> 3);    // XCD swizzle, bijective (800 % 8 == 0)
    int half = swz >= 400;
    int tile = swz - half * 400;
    int m0 = (tile & 15) * 128, n0 = (tile >> 4) * 128;   // 16 x 25 tiles
    float* C = half ? C1 : C0;
    int t = threadIdx.x;
    int w = t >> 6, l = t & 63;
    int wm = (w >> 1) * 64, wn = (w & 1) * 64;
    int lrow = l & 15, lc = l >> 4;
    int rsw = (lrow >> 1) & 3;
    int scol = ((l & 3) ^ ((l >> 3) & 3)) * 8;   // pre-swizzled source chunk
    int srowA = w * 32 + (l >> 2);

    f32x4 acc[4][4];
    #pragma unroll
    for (int i = 0; i < 4; i++)
        #pragma unroll
        for (int j = 0; j < 4; j++)
            acc[i][j] = {0.f, 0.f, 0.f, 0.f};

    const unsigned short* ga = &A[(size_t)(m0 + srowA) * K + half * 1024 + scol];
    const unsigned short* gb = &Bt[(size_t)(n0 + srowA) * K + half * 1024 + scol];

#define STAGE128(s, b) do { \
        const unsigned short* a0 = ga + (size_t)(s) * 32; \
        const unsigned short* b0 = gb + (size_t)(s) * 32; \
        gl_lds16(a0,                  &As[b][(w * 2 + 0) * 512]); \
        gl_lds16(a0 + 16 * (size_t)K, &As[b][(w * 2 + 1) * 512]); \
        gl_lds16(b0,                  &Bs[b][(w * 2 + 0) * 512]); \
        gl_lds16(b0 + 16 * (size_t)K, &Bs[b][(w * 2 + 1) * 512]); \
    } while (0)

#define GBODY128(rb) do { \
        bh8 af[4], bb[4]; \
        _Pragma("unroll") \
        for (int i = 0; i < 4; i++) \
            af[i] = *(const bh8*)(&As[rb][(wm + i * 16 + lrow) * 32 + ((lc ^ rsw) * 8)]); \
        _Pragma("unroll") \
        for (int j = 0; j < 4; j++) \
            bb[j] = *(const bh8*)(&Bs[rb][(wn + j * 16 + lrow) * 32 + ((lc ^ rsw) * 8)]); \
        _Pragma("unroll") \
        for (int i = 0; i < 4; i++) \
            _Pragma("unroll") \
            for (int j = 0; j < 4; j++) \
                acc[i][j] = __builtin_amdgcn_mfma_f32_16x16x32_bf16(af[i], bb[j], acc[i][j], 0, 0, 0); \
    } while (0)

#define WB4 asm volatile("s_waitcnt vmcnt(4)\n\ts_barrier" ::: "memory")

    // prologue: stage tiles 0,1 into bufs 0,1 (4 loads/wave each; 8 outstanding)
    STAGE128(0, 0);
    STAGE128(1, 1);
    // 32 K-steps (K_half=1024, BK=32). Main: s=0..29, unroll-3 (s%3 static).
    // Iter s: drain stage s (vmcnt(4)), barrier, stage s+2 into buf (s+2)%3
    // (last read at iter s-1; barrier-ordered), compute s.
    for (int sb = 0; sb < 30; sb += 3) {
        WB4;
        STAGE128(sb + 2, 2);
        GBODY128(0);
        WB4;
        STAGE128(sb + 3, 0);
        GBODY128(1);
        WB4;
        STAGE128(sb + 4, 1);
        GBODY128(2);
    }
    // peeled tail: s = 30 (buf 0, keep stage-31 in flight), s = 31 (buf 1, drain all)
    WB4;
    GBODY128(0);
    asm volatile("s_waitcnt vmcnt(0)\n\ts_barrier" ::: "memory");
    GBODY128(1);
#undef WB4
#undef STAGE128
#undef GBODY128
    int col = l & 15, rbase = (l >> 4) * 4;
    for (int i = 0; i < 4; i++)
        for (int j = 0; j < 4; j++)
            #pragma unroll
            for (int r = 0; r < 4; r++)
                C[(size_t)(m0 + wm + i * 16 + rbase + r) * ldc + (n0 + wn + j * 16 + col)] = acc[i][j][r];
}

// ---------------- out-proj NT GEMM, 64x128 tile (R7 structure, unchanged) ----------------
__global__ __launch_bounds__(256) void gemm_nt64_k(const unsigned short* __restrict__ A,
                                                   const unsigned short* __restrict__ Bt,
                                                   float* __restrict__ C,
                                                   int ldc, int mtiles) {
    const int K = 2048;
    __shared__ unsigned short As[3][64 * 32];
    __shared__ unsigned short Bs[3][128 * 32];
    int d = blockIdx.x;
    int nwg = gridDim.x;
    int cpx = nwg >> 3;
    int swz = (d & 7) * cpx + (d >> 3);
    int m0 = (swz % mtiles) * 64, n0 = (swz / mtiles) * 128;
    int t = threadIdx.x;
    int w = t >> 6, l = t & 63;
    int wm = (w >> 1) * 32, wn = (w & 1) * 64;
    int lrow = l & 15, lc = l >> 4;
    int rsw = (lrow >> 1) & 3;
    int scol = ((l & 3) ^ ((l >> 3) & 3)) * 8;

    f32x4 acc[2][4];
    #pragma unroll
    for (int i = 0; i < 2; i++)
        #pragma unroll
        for (int j = 0; j < 4; j++)
            acc[i][j] = {0.f, 0.f, 0.f, 0.f};

    const unsigned short* ga = &A[(size_t)(m0 + w * 16 + (l >> 2)) * K + scol];
    const unsigned short* gb = &Bt[(size_t)(n0 + w * 32 + (l >> 2)) * K + scol];

#define STAGE_NT64(s, b) do { \
        gl_lds16(ga + (size_t)(s) * 32,                  &As[b][w * 512]); \
        gl_lds16(gb + (size_t)(s) * 32,                  &Bs[b][(w * 2 + 0) * 512]); \
        gl_lds16(gb + (size_t)(s) * 32 + 16 * (size_t)K, &Bs[b][(w * 2 + 1) * 512]); \
    } while (0)

#define GBODY(rb) do { \
        bh8 af[2], bb[4]; \
        _Pragma("unroll") \
        for (int i = 0; i < 2; i++) \
            af[i] = *(const bh8*)(&As[rb][(wm + i * 16 + lrow) * 32 + ((lc ^ rsw) * 8)]); \
        _Pragma("unroll") \
        for (int j = 0; j < 4; j++) \
            bb[j] = *(const bh8*)(&Bs[rb][(wn + j * 16 + lrow) * 32 + ((lc ^ rsw) * 8)]); \
        _Pragma("unroll") \
        for (int i = 0; i < 2; i++) \
            _Pragma("unroll") \
            for (int j = 0; j < 4; j++) \
                acc[i][j] = __builtin_amdgcn_mfma_f32_16x16x32_bf16(af[i], bb[j], acc[i][j], 0, 0, 0); \
    } while (0)

#define WB3 asm volatile("s_waitcnt vmcnt(3)\n\ts_barrier" ::: "memory")

    STAGE_NT64(0, 0);
    STAGE_NT64(1, 1);
    for (int sb = 0; sb < 60; sb += 3) {
        WB3;
        STAGE_NT64(sb + 2, 2);
        GBODY(0);
        WB3;
        STAGE_NT64(sb + 3, 0);
        GBODY(1);
        WB3;
        STAGE_NT64(sb + 4, 1);
        GBODY(2);
    }
    WB3;
    STAGE_NT64(62, 2);
    GBODY(0);
    WB3;
    STAGE_NT64(63, 0);
    GBODY(1);
    WB3;
    GBODY(2);
    asm volatile("s_waitcnt vmcnt(0)\n\ts_barrier" ::: "memory");
    GBODY(0);
#undef WB3
#undef STAGE_NT64
#undef GBODY
    int col = l & 15, rbase = (l >> 4) * 4;
    for (int i = 0; i < 2; i++)
        for (int j = 0; j < 4; j++)
            #pragma unroll
            for (int r = 0; r < 4; r++)
                C[(size_t)(m0 + wm + i * 16 + rbase + r) * ldc + (n0 + wn + j * 16 + col)] = acc[i][j][r];
}

// ---------------- RMSNorm + RoPE for Q,K (sums split-K partials) ----------------
__global__ void norm_rope_k(const float* __restrict__ QKVG, const float* __restrict__ QKVG1,
                            unsigned short* __restrict__ Qr, unsigned short* __restrict__ Kr,
                            const float* __restrict__ g_q, const float* __restrict__ g_k) {
    int wid = blockIdx.x * (blockDim.x >> 6) + (threadIdx.x >> 6);
    int lane = threadIdx.x & 63;
    int type, s, hh;
    if (wid < SLEN * NHEAD) { type = 0; s = wid >> 5; hh = wid & 31; }
    else                    { int r = wid - SLEN * NHEAD; type = 1; s = r >> 3; hh = r & 7; }
    int col = (type == 0) ? hh * 64 + lane : 2080 + hh * 64 + lane;
    size_t idx = (size_t)s * NPAD + col;
    float x = QKVG[idx] + QKVG1[idx];
    float sq = x * x;
    #pragma unroll
    for (int off = 32; off; off >>= 1) sq += __shfl_xor(sq, off);
    float inv = rsqrtf(sq * (1.f / 64.f) + 1e-6f);
    float g = (type == 0 ? g_q : g_k)[lane];
    float xn = x * inv * g;
    float xp = __shfl_xor(xn, 32);
    float xr = (lane < 32) ? -xp : xp;
    int i = lane & 31;
    float invf = __expf(-(float)i * (0.03125f * 13.815510557964274f));
    float ang = (float)s * invf;
    float c = cosf(ang), sn = sinf(ang);
    float r = xn * c + xr * sn;
    if (type == 0) Qr[((size_t)hh * SLEN + s) * 64 + lane] = f2bf(r * QSCALE);
    else           Kr[((size_t)hh * SLEN + s) * 64 + lane] = f2bf(r);
}

// ---------------- V transpose + key-permute (sums split-K partials) ----------------
__global__ void vt_k(const float* __restrict__ QKVG, const float* __restrict__ QKVG1,
                     unsigned short* __restrict__ Vt) {
    __shared__ float tile[64][65];
    int s0 = blockIdx.x * 64, hh = blockIdx.y;
    int t = threadIdx.x;
    #pragma unroll
    for (int i = 0; i < 4; i++) {
        int idx = i * 256 + t;
        int sr = idx >> 4, c4 = (idx & 15) * 4;
        size_t off = (size_t)(s0 + sr) * NPAD + 2592 + hh * 64 + c4;
        float4 f = *(const float4*)(&QKVG[off]);
        float4 f1 = *(const float4*)(&QKVG1[off]);
        tile[sr][c4] = f.x + f1.x; tile[sr][c4 + 1] = f.y + f1.y;
        tile[sr][c4 + 2] = f.z + f1.z; tile[sr][c4 + 3] = f.w + f1.w;
    }
    __syncthreads();
    #pragma unroll
    for (int i = 0; i < 4; i++) {
        int idx = i * 256 + t;
        int dr = idx >> 4, c4 = (idx & 15) * 4;
        int hb = c4 >> 5, f = (c4 >> 4) & 1, g = (c4 >> 2) & 3;
        int p = (hb * 4 + g) * 8 + f * 4;
        ushort4 o;
        o.x = f2bf(tile[c4][dr]); o.y = f2bf(tile[c4 + 1][dr]);
        o.z = f2bf(tile[c4 + 2][dr]); o.w = f2bf(tile[c4 + 3][dr]);
        *(ushort4*)(&Vt[((size_t)hh * 64 + dr) * SLEN + s0 + p]) = o;
    }
}

// ---------------- sigmoid(gate) (sums split-K partials) ----------------
__global__ void gate_sig_k(const float* __restrict__ QKVG, const float* __restrict__ QKVG1,
                           float* __restrict__ gate) {
    int i = blockIdx.x * 256 + threadIdx.x;
    int s = i >> 5, h = i & 31;
    size_t idx = (size_t)s * NPAD + 2048 + h;
    float x = QKVG[idx] + QKVG1[idx];
    gate[i] = 1.f / (1.f + __expf(-x));
}

// ---------------- causal GQA flash attention + gate (R4 structure, unchanged) ----------------
__global__ __launch_bounds__(256) void attn_k(const unsigned short* __restrict__ Qr,
                                              const unsigned short* __restrict__ Kr,
                                              const unsigned short* __restrict__ Vt,
                                              const float* __restrict__ gate,
                                              unsigned short* __restrict__ attn) {
    __shared__ unsigned short Kls[3][64 * 64];
    __shared__ unsigned short Vls[3][64 * 64];
    int d = blockIdx.x;
    int kvh = d & 7;
    int h = kvh * 4 + ((d >> 3) & 3);
    int qt = 31 - (d >> 5);          // big-first: span-32 blocks dispatch first
    int t = threadIdx.x, w = t >> 6, l = t & 63;
    int ql = l & 15, g = l >> 4;
    const float NEGINF = -__builtin_inff();

    const unsigned short* Kh = Kr + (size_t)kvh * SLEN * 64;
    const unsigned short* Vh = Vt + (size_t)kvh * 64 * SLEN;
    const unsigned short* Qh = Qr + (size_t)h * SLEN * 64;
    int lk = g * 8;
    int r8 = l >> 3, c8 = l & 7;
    int cs = 8 * (c8 ^ r8);          // pre-swizzled source col (shorts)
    int R0 = w * 16, R1 = w * 16 + 8;
    int rdswz = (ql & 7) << 4;       // read-side XOR swizzle (bytes)

    int q0 = qt * 64;
    int qrow = q0 + w * 16 + ql;

    bh8 qa0 = *(const bh8*)(Qh + (size_t)qrow * 64 + lk);
    bh8 qa1 = *(const bh8*)(Qh + (size_t)qrow * 64 + 32 + lk);

    f32x4 o[4];
    #pragma unroll
    for (int i = 0; i < 4; i++) o[i] = {0.f, 0.f, 0.f, 0.f};
    float m2 = NEGINF, lsum = 0.f;

    int ntiles = qt + 1;
    {
        gl_lds16(&Kh[(size_t)(0 + R0 + r8) * 64 + cs], &Kls[0][R0 * 64]);
        gl_lds16(&Kh[(size_t)(0 + R1 + r8) * 64 + cs], &Kls[0][R1 * 64]);
        gl_lds16(&Vh[(size_t)(R0 + r8) * SLEN + 0 + cs], &Vls[0][R0 * 64]);
        gl_lds16(&Vh[(size_t)(R1 + r8) * SLEN + 0 + cs], &Vls[0][R1 * 64]);
    }
    if (ntiles > 1) {
        gl_lds16(&Kh[(size_t)(64 + R0 + r8) * 64 + cs], &Kls[1][R0 * 64]);
        gl_lds16(&Kh[(size_t)(64 + R1 + r8) * 64 + cs], &Kls[1][R1 * 64]);
        gl_lds16(&Vh[(size_t)(R0 + r8) * SLEN + 64 + cs], &Vls[1][R0 * 64]);
        gl_lds16(&Vh[(size_t)(R1 + r8) * SLEN + 64 + cs], &Vls[1][R1 * 64]);
    }
    int rd = 0, wr = 2;

    for (int ti = 0; ti < ntiles; ti++) {
        if (ti + 1 < ntiles) asm volatile("s_waitcnt vmcnt(4)\n\ts_barrier" ::: "memory");
        else                 asm volatile("s_waitcnt vmcnt(0)\n\ts_barrier" ::: "memory");
        if (ti + 2 < ntiles) {
            int kv1 = (ti + 2) * 64;
            gl_lds16(&Kh[(size_t)(kv1 + R0 + r8) * 64 + cs], &Kls[wr][R0 * 64]);
            gl_lds16(&Kh[(size_t)(kv1 + R1 + r8) * 64 + cs], &Kls[wr][R1 * 64]);
            gl_lds16(&Vh[(size_t)(R0 + r8) * SLEN + kv1 + cs], &Vls[wr][R0 * 64]);
            gl_lds16(&Vh[(size_t)(R1 + r8) * SLEN + kv1 + cs], &Vls[wr][R1 * 64]);
        }
        const unsigned short* Kb = &Kls[rd][0];
        const unsigned short* Vb = &Vls[rd][0];
        int kv0 = ti * 64;
        f32x4 sct[4];
        __builtin_amdgcn_s_setprio(1);
        #pragma unroll
        for (int nt = 0; nt < 4; nt++) {
            int rb = (nt * 16 + ql) * 128;
            bh8 kb0 = *(const bh8*)(&Kb[(rb + ((g * 16) ^ rdswz)) >> 1]);
            bh8 kb1 = *(const bh8*)(&Kb[(rb + ((64 + g * 16) ^ rdswz)) >> 1]);
            f32x4 a = {0.f, 0.f, 0.f, 0.f};
            a = __builtin_amdgcn_mfma_f32_16x16x32_bf16(kb0, qa0, a, 0, 0, 0);
            a = __builtin_amdgcn_mfma_f32_16x16x32_bf16(kb1, qa1, a, 0, 0, 0);
            sct[nt] = a;
        }
        __builtin_amdgcn_s_setprio(0);
        if (ti == qt) {
            #pragma unroll
            for (int nt = 0; nt < 4; nt++)
                #pragma unroll
                for (int j = 0; j < 4; j++) {
                    int key = kv0 + nt * 16 + 4 * g + j;
                    if (key > qrow) sct[nt][j] = NEGINF;
                }
        }
        float mt0 = fmaxf(fmaxf(sct[0][0], sct[0][1]), fmaxf(sct[0][2], sct[0][3]));
        float mt1 = fmaxf(fmaxf(sct[1][0], sct[1][1]), fmaxf(sct[1][2], sct[1][3]));
        float mt2 = fmaxf(fmaxf(sct[2][0], sct[2][1]), fmaxf(sct[2][2], sct[2][3]));
        float mt3 = fmaxf(fmaxf(sct[3][0], sct[3][1]), fmaxf(sct[3][2], sct[3][3]));
        float mt = fmaxf(fmaxf(mt0, mt1), fmaxf(mt2, mt3));
        mt = fmaxf(mt, __shfl_xor(mt, 16));
        mt = fmaxf(mt, __shfl_xor(mt, 32));
        if (!__all(mt - m2 <= 8.f)) {
            float mnew = fmaxf(m2, mt);
            float resc = __builtin_amdgcn_exp2f(m2 - mnew);
            m2 = mnew;
            lsum *= resc;
            float rf[4];
            #pragma unroll
            for (int j = 0; j < 4; j++) rf[j] = __shfl(resc, 4 * g + j);
            #pragma unroll
            for (int nt = 0; nt < 4; nt++) {
                f32x4 oo = o[nt];
                #pragma unroll
                for (int j = 0; j < 4; j++) oo[j] *= rf[j];
                o[nt] = oo;
            }
        }
        float ps = 0.f;
        #pragma unroll
        for (int nt = 0; nt < 4; nt++)
            #pragma unroll
            for (int j = 0; j < 4; j++) {
                float p = __builtin_amdgcn_exp2f(sct[nt][j] - m2);
                sct[nt][j] = p;
                ps += p;
            }
        ps += __shfl_xor(ps, 16);
        ps += __shfl_xor(ps, 32);
        lsum += ps;
        union { unsigned int u[4]; bh8 v; } pa0, pa1;
        pa0.u[0] = cvtpk_bf16(sct[0][0], sct[0][1]);
        pa0.u[1] = cvtpk_bf16(sct[0][2], sct[0][3]);
        pa0.u[2] = cvtpk_bf16(sct[1][0], sct[1][1]);
        pa0.u[3] = cvtpk_bf16(sct[1][2], sct[1][3]);
        pa1.u[0] = cvtpk_bf16(sct[2][0], sct[2][1]);
        pa1.u[1] = cvtpk_bf16(sct[2][2], sct[2][3]);
        pa1.u[2] = cvtpk_bf16(sct[3][0], sct[3][1]);
        pa1.u[3] = cvtpk_bf16(sct[3][2], sct[3][3]);
        __builtin_amdgcn_s_setprio(1);
        #pragma unroll
        for (int nt = 0; nt < 4; nt++) {
            int rb = (nt * 16 + ql) * 128;
            bh8 vb0 = *(const bh8*)(&Vb[(rb + ((g * 16) ^ rdswz)) >> 1]);
            bh8 vb1 = *(const bh8*)(&Vb[(rb + ((64 + g * 16) ^ rdswz)) >> 1]);
            o[nt] = __builtin_amdgcn_mfma_f32_16x16x32_bf16(pa0.v, vb0, o[nt], 0, 0, 0);
            o[nt] = __builtin_amdgcn_mfma_f32_16x16x32_bf16(pa1.v, vb1, o[nt], 0, 0, 0);
        }
        __builtin_amdgcn_s_setprio(0);
        rd = (rd == 2) ? 0 : rd + 1;
        wr = (wr == 2) ? 0 : wr + 1;
    }

    float gf[4];
    #pragma unroll
    for (int j = 0; j < 4; j++) {
        float ls = __shfl(lsum, 4 * g + j);
        int row = q0 + w * 16 + 4 * g + j;
        gf[j] = gate[row * 32 + h] / ls;
    }
    #pragma unroll
    for (int j = 0; j < 4; j++) {
        int row = q0 + w * 16 + 4 * g + j;
        #pragma unroll
        for (int nt = 0; nt < 4; nt++)
            attn[(size_t)row * 2048 + h * 64 + nt * 16 + ql] = f2bf(o[nt][j] * gf[j]);
    }
}

extern "C" void kernel_launch(void* const* d_in, const int* in_sizes, int n_in,
                              void* d_out, int out_size, void* d_ws, size_t ws_size,
                              hipStream_t stream) {
    const float* hidden = (const float*)d_in[0];
    const float* Wq = (const float*)d_in[1];
    const float* Wk = (const float*)d_in[2];
    const float* Wv = (const float*)d_in[3];
    const float* Wo = (const float*)d_in[4];
    const float* gq = (const float*)d_in[5];
    const float* gk = (const float*)d_in[6];
    float* out = (float*)d_out;
    char* ws = (char*)d_ws;

    unsigned short* X     = (unsigned short*)(ws + 0);         //  8388608 B
    unsigned short* Wt    = (unsigned short*)(ws + 8388608);   // 13107200 B
    float*          QKVG  = (float*)(ws + 21495808);           // 26214400 B
    unsigned short* Qr    = (unsigned short*)(ws + 47710208);  //  8388608 B
    unsigned short* Kr    = (unsigned short*)(ws + 56098816);  //  2097152 B
    unsigned short* Vt    = (unsigned short*)(ws + 58195968);  //  2097152 B
    float*          gate  = (float*)(ws + 60293120);           //   262144 B
    unsigned short* attn  = (unsigned short*)(ws + 60555264);  //  8388608 B
    unsigned short* Wot   = (unsigned short*)(ws + 68943872);  //  8388608 B
    float*          QKVG1 = (float*)(ws + 77332480);           // 26214400 B (split-K partial)

    cast_x_k<<<dim3(4096), dim3(256), 0, stream>>>(hidden, X, SLEN * HDIM);
    pack_wt_k<<<dim3(100, 64), dim3(256), 0, stream>>>(Wq, Wk, Wv, Wt);
    pack_wot_k<<<dim3(64, 64), dim3(256), 0, stream>>>(Wo, Wot);
    gemm_nt128_k<<<dim3(800), dim3(256), 0, stream>>>(X, Wt, QKVG, QKVG1);
    norm_rope_k<<<dim3(20480), dim3(256), 0, stream>>>(QKVG, QKVG1, Qr, Kr, gq, gk);
    vt_k<<<dim3(32, 8), dim3(256), 0, stream>>>(QKVG, QKVG1, Vt);
    gate_sig_k<<<dim3(256), dim3(256), 0, stream>>>(QKVG, QKVG1, gate);
    attn_k<<<dim3(1024), dim3(256), 0, stream>>>(Qr, Kr, Vt, gate, attn);
    gemm_nt64_k<<<dim3(512), dim3(256), 0, stream>>>(attn, Wot, out, 2048, 32);
}

// Round 10
// 169.879 us; speedup vs baseline: 1.0183x; 1.0051x over previous
//
#include <hip/hip_runtime.h>
#include <hip/hip_bf16.h>

#define SLEN 2048
#define HDIM 2048
#define NHEAD 32
#define KVHEAD 8
#define HEADD 64
#define NTOT 3104
#define NPAD 3200

typedef short bh8 __attribute__((ext_vector_type(8)));
typedef float f32x4 __attribute__((ext_vector_type(4)));

// 0.125 * log2(e): folded into Q so QK^T MFMA emits log2-domain scores
#define QSCALE 0.1803368801111204f

__device__ __forceinline__ unsigned short f2bf(float f) {
    union { float f; unsigned int u; } v; v.f = f;
    unsigned int u = v.u;
    return (unsigned short)((u + 0x7fffu + ((u >> 16) & 1u)) >> 16);
}

// HW packed f32->bf16 (RNE), 1 instruction instead of ~10 bit-ops
__device__ __forceinline__ unsigned int cvtpk_bf16(float lo, float hi) {
    unsigned int r;
    asm("v_cvt_pk_bf16_f32 %0, %1, %2" : "=v"(r) : "v"(lo), "v"(hi));
    return r;
}

__device__ __forceinline__ void gl_lds16(const unsigned short* g, unsigned short* l) {
    __builtin_amdgcn_global_load_lds(
        (const __attribute__((address_space(1))) unsigned int*)g,
        (__attribute__((address_space(3))) unsigned int*)l, 16, 0, 0);
}

// ---------------- cast hidden fp32 -> bf16 ----------------
__global__ void cast_x_k(const float* __restrict__ src, unsigned short* __restrict__ dst, int n) {
    int i = blockIdx.x * blockDim.x + threadIdx.x;
    int base = i * 4;
    if (base < n) {
        float4 f = *(const float4*)(src + base);
        ushort4 o;
        o.x = f2bf(f.x); o.y = f2bf(f.y); o.z = f2bf(f.z); o.w = f2bf(f.w);
        *(ushort4*)(dst + base) = o;
    }
}

// ---------------- pack [Wq|gates|Wk|Wv] transposed -> bf16 (NPAD x HDIM) ----------------
__global__ void pack_wt_k(const float* __restrict__ Wq, const float* __restrict__ Wk,
                          const float* __restrict__ Wv, unsigned short* __restrict__ Wt) {
    __shared__ float tile[32][33];
    int n0 = blockIdx.x * 32, k0 = blockIdx.y * 32;
    int t = threadIdx.x;
    for (int i = 0; i < 4; i++) {
        int idx = i * 256 + t;
        int kr = idx >> 5, nc = idx & 31;
        int n = n0 + nc, k = k0 + kr;
        float val = 0.f;
        if (n < 2048)       { int h = n >> 6, d = n & 63; val = Wq[(size_t)k * 2080 + (h >> 2) * 260 + (h & 3) * 64 + d]; }
        else if (n < 2080)  { int h = n - 2048;           val = Wq[(size_t)k * 2080 + (h >> 2) * 260 + 256 + (h & 3)]; }
        else if (n < 2592)  { val = Wk[(size_t)k * 512 + (n - 2080)]; }
        else if (n < 3104)  { val = Wv[(size_t)k * 512 + (n - 2592)]; }
        tile[kr][nc] = val;
    }
    __syncthreads();
    for (int i = 0; i < 4; i++) {
        int idx = i * 256 + t;
        int nr = idx >> 5, kc = idx & 31;
        Wt[(size_t)(n0 + nr) * HDIM + (k0 + kc)] = f2bf(tile[kc][nr]);
    }
}

// ---------------- transpose-cast Wo -> bf16 (2048 x 2048) ----------------
__global__ void pack_wot_k(const float* __restrict__ Wo, unsigned short* __restrict__ Wt) {
    __shared__ float tile[32][33];
    int n0 = blockIdx.x * 32, k0 = blockIdx.y * 32;
    int t = threadIdx.x;
    for (int i = 0; i < 4; i++) {
        int idx = i * 256 + t;
        int kr = idx >> 5, nc = idx & 31;
        tile[kr][nc] = Wo[(size_t)(k0 + kr) * 2048 + (n0 + nc)];
    }
    __syncthreads();
    for (int i = 0; i < 4; i++) {
        int idx = i * 256 + t;
        int nr = idx >> 5, kc = idx & 31;
        Wt[(size_t)(n0 + nr) * 2048 + (k0 + kc)] = f2bf(tile[kc][nr]);
    }
}

// ---------------- NT GEMM, 64x128 tile, templated K-steps (R10) ----------------
// R7's proven structure (3-buf counted vmcnt(3) + static indices + chunk swizzle),
// templated on NST (K-steps): NST=64 for QKV (800 blocks, row-stride 2048),
// NST=32 for out-proj split-K x2 (1024 blocks, halves write partials C0/C1).
// ntiles = tiles per K-half; swz >= ntiles selects half 2 with koff = NST*32.
template<int NST>
__global__ __launch_bounds__(256) void gemm_nt64_k(const unsigned short* __restrict__ A,
                                                   const unsigned short* __restrict__ Bt,
                                                   float* __restrict__ C0,
                                                   float* __restrict__ C1,
                                                   int ldc, int mtiles, int ntiles) {
    const int K = 2048;
    __shared__ unsigned short As[3][64 * 32];
    __shared__ unsigned short Bs[3][128 * 32];
    int d = blockIdx.x;
    int nwg = gridDim.x;
    int cpx = nwg >> 3;
    int swz = (d & 7) * cpx + (d >> 3);
    int half = (swz >= ntiles) ? 1 : 0;
    int tile = swz - half * ntiles;
    int m0 = (tile % mtiles) * 64, n0 = (tile / mtiles) * 128;
    float* C = half ? C1 : C0;
    int koff = half * (NST * 32);
    int t = threadIdx.x;
    int w = t >> 6, l = t & 63;
    int wm = (w >> 1) * 32, wn = (w & 1) * 64;
    int lrow = l & 15, lc = l >> 4;
    int rsw = (lrow >> 1) & 3;
    int scol = ((l & 3) ^ ((l >> 3) & 3)) * 8;

    f32x4 acc[2][4];
    #pragma unroll
    for (int i = 0; i < 2; i++)
        #pragma unroll
        for (int j = 0; j < 4; j++)
            acc[i][j] = {0.f, 0.f, 0.f, 0.f};

    const unsigned short* ga = &A[(size_t)(m0 + w * 16 + (l >> 2)) * K + koff + scol];
    const unsigned short* gb = &Bt[(size_t)(n0 + w * 32 + (l >> 2)) * K + koff + scol];

#define STAGE_NT64(s, b) do { \
        gl_lds16(ga + (size_t)(s) * 32,                  &As[b][w * 512]); \
        gl_lds16(gb + (size_t)(s) * 32,                  &Bs[b][(w * 2 + 0) * 512]); \
        gl_lds16(gb + (size_t)(s) * 32 + 16 * (size_t)K, &Bs[b][(w * 2 + 1) * 512]); \
    } while (0)

#define GBODY(rb) do { \
        bh8 af[2], bb[4]; \
        _Pragma("unroll") \
        for (int i = 0; i < 2; i++) \
            af[i] = *(const bh8*)(&As[rb][(wm + i * 16 + lrow) * 32 + ((lc ^ rsw) * 8)]); \
        _Pragma("unroll") \
        for (int j = 0; j < 4; j++) \
            bb[j] = *(const bh8*)(&Bs[rb][(wn + j * 16 + lrow) * 32 + ((lc ^ rsw) * 8)]); \
        _Pragma("unroll") \
        for (int i = 0; i < 2; i++) \
            _Pragma("unroll") \
            for (int j = 0; j < 4; j++) \
                acc[i][j] = __builtin_amdgcn_mfma_f32_16x16x32_bf16(af[i], bb[j], acc[i][j], 0, 0, 0); \
    } while (0)

#define WB3 asm volatile("s_waitcnt vmcnt(3)\n\ts_barrier" ::: "memory")

    STAGE_NT64(0, 0);
    STAGE_NT64(1, 1);
    if constexpr (NST == 64) {
        for (int sb = 0; sb < 60; sb += 3) {
            WB3;
            STAGE_NT64(sb + 2, 2);
            GBODY(0);
            WB3;
            STAGE_NT64(sb + 3, 0);
            GBODY(1);
            WB3;
            STAGE_NT64(sb + 4, 1);
            GBODY(2);
        }
        WB3;
        STAGE_NT64(62, 2);
        GBODY(0);
        WB3;
        STAGE_NT64(63, 0);
        GBODY(1);
        WB3;
        GBODY(2);
        asm volatile("s_waitcnt vmcnt(0)\n\ts_barrier" ::: "memory");
        GBODY(0);
    } else {
        // NST == 32: main s=0..29 (unroll-3, stages up to 31), tail s=30 (buf0), 31 (buf1)
        for (int sb = 0; sb < 30; sb += 3) {
            WB3;
            STAGE_NT64(sb + 2, 2);
            GBODY(0);
            WB3;
            STAGE_NT64(sb + 3, 0);
            GBODY(1);
            WB3;
            STAGE_NT64(sb + 4, 1);
            GBODY(2);
        }
        WB3;
        GBODY(0);
        asm volatile("s_waitcnt vmcnt(0)\n\ts_barrier" ::: "memory");
        GBODY(1);
    }
#undef WB3
#undef STAGE_NT64
#undef GBODY
    int col = l & 15, rbase = (l >> 4) * 4;
    for (int i = 0; i < 2; i++)
        for (int j = 0; j < 4; j++)
            #pragma unroll
            for (int r = 0; r < 4; r++)
                C[(size_t)(m0 + wm + i * 16 + rbase + r) * ldc + (n0 + wn + j * 16 + col)] = acc[i][j][r];
}

// ---------------- out-proj split-K reduce: out = P0 + P1 (2048^2 f32) ----------------
__global__ void addf4_k(const float* __restrict__ a, const float* __restrict__ b,
                        float* __restrict__ o) {
    int i = (blockIdx.x * 256 + threadIdx.x) * 4;
    float4 x = *(const float4*)(a + i);
    float4 y = *(const float4*)(b + i);
    float4 r; r.x = x.x + y.x; r.y = x.y + y.y; r.z = x.z + y.z; r.w = x.w + y.w;
    *(float4*)(o + i) = r;
}

// ---------------- fused QKVG consumers: RMSNorm+RoPE | V-transpose | gate ----------------
// R10: one dispatch, branch by blockIdx range (bodies verbatim from the 3 old kernels).
// blocks [0,20480): norm_rope (4 wave-tasks/block); [20480,20736): vt; [20736,20992): gate.
__global__ void post_qkv_k(const float* __restrict__ QKVG,
                           unsigned short* __restrict__ Qr, unsigned short* __restrict__ Kr,
                           unsigned short* __restrict__ Vt, float* __restrict__ gate,
                           const float* __restrict__ g_q, const float* __restrict__ g_k) {
    __shared__ float tile[64][65];
    int b = blockIdx.x;
    if (b < 20480) {
        int wid = b * 4 + (threadIdx.x >> 6);
        int lane = threadIdx.x & 63;
        int type, s, hh;
        if (wid < SLEN * NHEAD) { type = 0; s = wid >> 5; hh = wid & 31; }
        else                    { int r = wid - SLEN * NHEAD; type = 1; s = r >> 3; hh = r & 7; }
        int col = (type == 0) ? hh * 64 + lane : 2080 + hh * 64 + lane;
        float x = QKVG[(size_t)s * NPAD + col];
        float sq = x * x;
        #pragma unroll
        for (int off = 32; off; off >>= 1) sq += __shfl_xor(sq, off);
        float inv = rsqrtf(sq * (1.f / 64.f) + 1e-6f);
        float g = (type == 0 ? g_q : g_k)[lane];
        float xn = x * inv * g;
        float xp = __shfl_xor(xn, 32);
        float xr = (lane < 32) ? -xp : xp;
        int i = lane & 31;
        float invf = __expf(-(float)i * (0.03125f * 13.815510557964274f));
        float ang = (float)s * invf;
        float c = cosf(ang), sn = sinf(ang);
        float r = xn * c + xr * sn;
        if (type == 0) Qr[((size_t)hh * SLEN + s) * 64 + lane] = f2bf(r * QSCALE);
        else           Kr[((size_t)hh * SLEN + s) * 64 + lane] = f2bf(r);
    } else if (b < 20736) {
        int b2 = b - 20480;
        int hh = b2 >> 5, s0 = (b2 & 31) * 64;
        int t = threadIdx.x;
        #pragma unroll
        for (int i = 0; i < 4; i++) {
            int idx = i * 256 + t;
            int sr = idx >> 4, c4 = (idx & 15) * 4;
            float4 f = *(const float4*)(&QKVG[(size_t)(s0 + sr) * NPAD + 2592 + hh * 64 + c4]);
            tile[sr][c4] = f.x; tile[sr][c4 + 1] = f.y; tile[sr][c4 + 2] = f.z; tile[sr][c4 + 3] = f.w;
        }
        __syncthreads();
        #pragma unroll
        for (int i = 0; i < 4; i++) {
            int idx = i * 256 + t;
            int dr = idx >> 4, c4 = (idx & 15) * 4;
            int hb = c4 >> 5, f = (c4 >> 4) & 1, g = (c4 >> 2) & 3;
            int p = (hb * 4 + g) * 8 + f * 4;
            ushort4 o;
            o.x = f2bf(tile[c4][dr]); o.y = f2bf(tile[c4 + 1][dr]);
            o.z = f2bf(tile[c4 + 2][dr]); o.w = f2bf(tile[c4 + 3][dr]);
            *(ushort4*)(&Vt[((size_t)hh * 64 + dr) * SLEN + s0 + p]) = o;
        }
    } else {
        int b2 = b - 20736;
        int i = b2 * 256 + threadIdx.x;
        int s = i >> 5, h = i & 31;
        float x = QKVG[(size_t)s * NPAD + 2048 + h];
        gate[i] = 1.f / (1.f + __expf(-x));
    }
}

// ---------------- causal GQA flash attention + gate (R4 structure, unchanged) ----------------
__global__ __launch_bounds__(256) void attn_k(const unsigned short* __restrict__ Qr,
                                              const unsigned short* __restrict__ Kr,
                                              const unsigned short* __restrict__ Vt,
                                              const float* __restrict__ gate,
                                              unsigned short* __restrict__ attn) {
    __shared__ unsigned short Kls[3][64 * 64];
    __shared__ unsigned short Vls[3][64 * 64];
    int d = blockIdx.x;
    int kvh = d & 7;
    int h = kvh * 4 + ((d >> 3) & 3);
    int qt = 31 - (d >> 5);          // big-first: span-32 blocks dispatch first
    int t = threadIdx.x, w = t >> 6, l = t & 63;
    int ql = l & 15, g = l >> 4;
    const float NEGINF = -__builtin_inff();

    const unsigned short* Kh = Kr + (size_t)kvh * SLEN * 64;
    const unsigned short* Vh = Vt + (size_t)kvh * 64 * SLEN;
    const unsigned short* Qh = Qr + (size_t)h * SLEN * 64;
    int lk = g * 8;
    int r8 = l >> 3, c8 = l & 7;
    int cs = 8 * (c8 ^ r8);          // pre-swizzled source col (shorts)
    int R0 = w * 16, R1 = w * 16 + 8;
    int rdswz = (ql & 7) << 4;       // read-side XOR swizzle (bytes)

    int q0 = qt * 64;
    int qrow = q0 + w * 16 + ql;

    bh8 qa0 = *(const bh8*)(Qh + (size_t)qrow * 64 + lk);
    bh8 qa1 = *(const bh8*)(Qh + (size_t)qrow * 64 + 32 + lk);

    f32x4 o[4];
    #pragma unroll
    for (int i = 0; i < 4; i++) o[i] = {0.f, 0.f, 0.f, 0.f};
    float m2 = NEGINF, lsum = 0.f;

    int ntiles = qt + 1;
    {
        gl_lds16(&Kh[(size_t)(0 + R0 + r8) * 64 + cs], &Kls[0][R0 * 64]);
        gl_lds16(&Kh[(size_t)(0 + R1 + r8) * 64 + cs], &Kls[0][R1 * 64]);
        gl_lds16(&Vh[(size_t)(R0 + r8) * SLEN + 0 + cs], &Vls[0][R0 * 64]);
        gl_lds16(&Vh[(size_t)(R1 + r8) * SLEN + 0 + cs], &Vls[0][R1 * 64]);
    }
    if (ntiles > 1) {
        gl_lds16(&Kh[(size_t)(64 + R0 + r8) * 64 + cs], &Kls[1][R0 * 64]);
        gl_lds16(&Kh[(size_t)(64 + R1 + r8) * 64 + cs], &Kls[1][R1 * 64]);
        gl_lds16(&Vh[(size_t)(R0 + r8) * SLEN + 64 + cs], &Vls[1][R0 * 64]);
        gl_lds16(&Vh[(size_t)(R1 + r8) * SLEN + 64 + cs], &Vls[1][R1 * 64]);
    }
    int rd = 0, wr = 2;

    for (int ti = 0; ti < ntiles; ti++) {
        if (ti + 1 < ntiles) asm volatile("s_waitcnt vmcnt(4)\n\ts_barrier" ::: "memory");
        else                 asm volatile("s_waitcnt vmcnt(0)\n\ts_barrier" ::: "memory");
        if (ti + 2 < ntiles) {
            int kv1 = (ti + 2) * 64;
            gl_lds16(&Kh[(size_t)(kv1 + R0 + r8) * 64 + cs], &Kls[wr][R0 * 64]);
            gl_lds16(&Kh[(size_t)(kv1 + R1 + r8) * 64 + cs], &Kls[wr][R1 * 64]);
            gl_lds16(&Vh[(size_t)(R0 + r8) * SLEN + kv1 + cs], &Vls[wr][R0 * 64]);
            gl_lds16(&Vh[(size_t)(R1 + r8) * SLEN + kv1 + cs], &Vls[wr][R1 * 64]);
        }
        const unsigned short* Kb = &Kls[rd][0];
        const unsigned short* Vb = &Vls[rd][0];
        int kv0 = ti * 64;
        f32x4 sct[4];
        __builtin_amdgcn_s_setprio(1);
        #pragma unroll
        for (int nt = 0; nt < 4; nt++) {
            int rb = (nt * 16 + ql) * 128;
            bh8 kb0 = *(const bh8*)(&Kb[(rb + ((g * 16) ^ rdswz)) >> 1]);
            bh8 kb1 = *(const bh8*)(&Kb[(rb + ((64 + g * 16) ^ rdswz)) >> 1]);
            f32x4 a = {0.f, 0.f, 0.f, 0.f};
            a = __builtin_amdgcn_mfma_f32_16x16x32_bf16(kb0, qa0, a, 0, 0, 0);
            a = __builtin_amdgcn_mfma_f32_16x16x32_bf16(kb1, qa1, a, 0, 0, 0);
            sct[nt] = a;
        }
        __builtin_amdgcn_s_setprio(0);
        if (ti == qt) {
            #pragma unroll
            for (int nt = 0; nt < 4; nt++)
                #pragma unroll
                for (int j = 0; j < 4; j++) {
                    int key = kv0 + nt * 16 + 4 * g + j;
                    if (key > qrow) sct[nt][j] = NEGINF;
                }
        }
        float mt0 = fmaxf(fmaxf(sct[0][0], sct[0][1]), fmaxf(sct[0][2], sct[0][3]));
        float mt1 = fmaxf(fmaxf(sct[1][0], sct[1][1]), fmaxf(sct[1][2], sct[1][3]));
        float mt2 = fmaxf(fmaxf(sct[2][0], sct[2][1]), fmaxf(sct[2][2], sct[2][3]));
        float mt3 = fmaxf(fmaxf(sct[3][0], sct[3][1]), fmaxf(sct[3][2], sct[3][3]));
        float mt = fmaxf(fmaxf(mt0, mt1), fmaxf(mt2, mt3));
        mt = fmaxf(mt, __shfl_xor(mt, 16));
        mt = fmaxf(mt, __shfl_xor(mt, 32));
        if (!__all(mt - m2 <= 8.f)) {
            float mnew = fmaxf(m2, mt);
            float resc = __builtin_amdgcn_exp2f(m2 - mnew);
            m2 = mnew;
            lsum *= resc;
            float rf[4];
            #pragma unroll
            for (int j = 0; j < 4; j++) rf[j] = __shfl(resc, 4 * g + j);
            #pragma unroll
            for (int nt = 0; nt < 4; nt++) {
                f32x4 oo = o[nt];
                #pragma unroll
                for (int j = 0; j < 4; j++) oo[j] *= rf[j];
                o[nt] = oo;
            }
        }
        float ps = 0.f;
        #pragma unroll
        for (int nt = 0; nt < 4; nt++)
            #pragma unroll
            for (int j = 0; j < 4; j++) {
                float p = __builtin_amdgcn_exp2f(sct[nt][j] - m2);
                sct[nt][j] = p;
                ps += p;
            }
        ps += __shfl_xor(ps, 16);
        ps += __shfl_xor(ps, 32);
        lsum += ps;
        union { unsigned int u[4]; bh8 v; } pa0, pa1;
        pa0.u[0] = cvtpk_bf16(sct[0][0], sct[0][1]);
        pa0.u[1] = cvtpk_bf16(sct[0][2], sct[0][3]);
        pa0.u[2] = cvtpk_bf16(sct[1][0], sct[1][1]);
        pa0.u[3] = cvtpk_bf16(sct[1][2], sct[1][3]);
        pa1.u[0] = cvtpk_bf16(sct[2][0], sct[2][1]);
        pa1.u[1] = cvtpk_bf16(sct[2][2], sct[2][3]);
        pa1.u[2] = cvtpk_bf16(sct[3][0], sct[3][1]);
        pa1.u[3] = cvtpk_bf16(sct[3][2], sct[3][3]);
        __builtin_amdgcn_s_setprio(1);
        #pragma unroll
        for (int nt = 0; nt < 4; nt++) {
            int rb = (nt * 16 + ql) * 128;
            bh8 vb0 = *(const bh8*)(&Vb[(rb + ((g * 16) ^ rdswz)) >> 1]);
            bh8 vb1 = *(const bh8*)(&Vb[(rb + ((64 + g * 16) ^ rdswz)) >> 1]);
            o[nt] = __builtin_amdgcn_mfma_f32_16x16x32_bf16(pa0.v, vb0, o[nt], 0, 0, 0);
            o[nt] = __builtin_amdgcn_mfma_f32_16x16x32_bf16(pa1.v, vb1, o[nt], 0, 0, 0);
        }
        __builtin_amdgcn_s_setprio(0);
        rd = (rd == 2) ? 0 : rd + 1;
        wr = (wr == 2) ? 0 : wr + 1;
    }

    float gf[4];
    #pragma unroll
    for (int j = 0; j < 4; j++) {
        float ls = __shfl(lsum, 4 * g + j);
        int row = q0 + w * 16 + 4 * g + j;
        gf[j] = gate[row * 32 + h] / ls;
    }
    #pragma unroll
    for (int j = 0; j < 4; j++) {
        int row = q0 + w * 16 + 4 * g + j;
        #pragma unroll
        for (int nt = 0; nt < 4; nt++)
            attn[(size_t)row * 2048 + h * 64 + nt * 16 + ql] = f2bf(o[nt][j] * gf[j]);
    }
}

extern "C" void kernel_launch(void* const* d_in, const int* in_sizes, int n_in,
                              void* d_out, int out_size, void* d_ws, size_t ws_size,
                              hipStream_t stream) {
    const float* hidden = (const float*)d_in[0];
    const float* Wq = (const float*)d_in[1];
    const float* Wk = (const float*)d_in[2];
    const float* Wv = (const float*)d_in[3];
    const float* Wo = (const float*)d_in[4];
    const float* gq = (const float*)d_in[5];
    const float* gk = (const float*)d_in[6];
    float* out = (float*)d_out;
    char* ws = (char*)d_ws;

    unsigned short* X     = (unsigned short*)(ws + 0);         //  8388608 B
    unsigned short* Wt    = (unsigned short*)(ws + 8388608);   // 13107200 B
    float*          QKVG  = (float*)(ws + 21495808);           // 26214400 B (reused as P0 after consumers)
    unsigned short* Qr    = (unsigned short*)(ws + 47710208);  //  8388608 B
    unsigned short* Kr    = (unsigned short*)(ws + 56098816);  //  2097152 B
    unsigned short* Vt    = (unsigned short*)(ws + 58195968);  //  2097152 B
    float*          gate  = (float*)(ws + 60293120);           //   262144 B
    unsigned short* attnb = (unsigned short*)(ws + 60555264);  //  8388608 B
    unsigned short* Wot   = (unsigned short*)(ws + 68943872);  //  8388608 B
    float*          P1    = (float*)(ws + 77332480);           // 16777216 B (out-proj split-K partial)
    float*          P0    = QKVG;                              // dead after post_qkv_k

    cast_x_k<<<dim3(4096), dim3(256), 0, stream>>>(hidden, X, SLEN * HDIM);
    pack_wt_k<<<dim3(100, 64), dim3(256), 0, stream>>>(Wq, Wk, Wv, Wt);
    pack_wot_k<<<dim3(64, 64), dim3(256), 0, stream>>>(Wo, Wot);
    gemm_nt64_k<64><<<dim3(800), dim3(256), 0, stream>>>(X, Wt, QKVG, QKVG, NPAD, 32, 800);
    post_qkv_k<<<dim3(20992), dim3(256), 0, stream>>>(QKVG, Qr, Kr, Vt, gate, gq, gk);
    attn_k<<<dim3(1024), dim3(256), 0, stream>>>(Qr, Kr, Vt, gate, attnb);
    gemm_nt64_k<32><<<dim3(1024), dim3(256), 0, stream>>>(attnb, Wot, P0, P1, 2048, 32, 512);
    addf4_k<<<dim3(4096), dim3(256), 0, stream>>>(P0, P1, out);
}

// Round 11
// 160.065 us; speedup vs baseline: 1.0807x; 1.0613x over previous
//
#include <hip/hip_runtime.h>
#include <hip/hip_bf16.h>

#define SLEN 2048
#define HDIM 2048
#define NHEAD 32
#define KVHEAD 8
#define HEADD 64
#define NTOT 3104
#define NPAD 3200

typedef short bh8 __attribute__((ext_vector_type(8)));
typedef float f32x4 __attribute__((ext_vector_type(4)));

// 0.125 * log2(e): folded into Q so QK^T MFMA emits log2-domain scores
#define QSCALE 0.1803368801111204f

__device__ __forceinline__ unsigned short f2bf(float f) {
    union { float f; unsigned int u; } v; v.f = f;
    unsigned int u = v.u;
    return (unsigned short)((u + 0x7fffu + ((u >> 16) & 1u)) >> 16);
}

// HW packed f32->bf16 (RNE), 1 instruction instead of ~10 bit-ops
__device__ __forceinline__ unsigned int cvtpk_bf16(float lo, float hi) {
    unsigned int r;
    asm("v_cvt_pk_bf16_f32 %0, %1, %2" : "=v"(r) : "v"(lo), "v"(hi));
    return r;
}

__device__ __forceinline__ void gl_lds16(const unsigned short* g, unsigned short* l) {
    __builtin_amdgcn_global_load_lds(
        (const __attribute__((address_space(1))) unsigned int*)g,
        (__attribute__((address_space(3))) unsigned int*)l, 16, 0, 0);
}

// ---------------- cast hidden fp32 -> bf16 ----------------
__global__ void cast_x_k(const float* __restrict__ src, unsigned short* __restrict__ dst, int n) {
    int i = blockIdx.x * blockDim.x + threadIdx.x;
    int base = i * 4;
    if (base < n) {
        float4 f = *(const float4*)(src + base);
        ushort4 o;
        o.x = f2bf(f.x); o.y = f2bf(f.y); o.z = f2bf(f.z); o.w = f2bf(f.w);
        *(ushort4*)(dst + base) = o;
    }
}

// ---------------- pack [Q | K | V | gates] transposed -> bf16 (NPAD x HDIM) ----------------
// R11 layout: Q 0..2047, K 2048..2559, V 2560..3071, gates 3072..3103, pad to 3200.
// K/V heads are now 64-aligned so each GEMM wave's 64-col tile = exactly one head
// (enables the fused RMSNorm+RoPE epilogue in gemm_nt64_k<.,true>).
__global__ void pack_wt_k(const float* __restrict__ Wq, const float* __restrict__ Wk,
                          const float* __restrict__ Wv, unsigned short* __restrict__ Wt) {
    __shared__ float tile[32][33];
    int n0 = blockIdx.x * 32, k0 = blockIdx.y * 32;
    int t = threadIdx.x;
    for (int i = 0; i < 4; i++) {
        int idx = i * 256 + t;
        int kr = idx >> 5, nc = idx & 31;
        int n = n0 + nc, k = k0 + kr;
        float val = 0.f;
        if (n < 2048)       { int h = n >> 6, d = n & 63; val = Wq[(size_t)k * 2080 + (h >> 2) * 260 + (h & 3) * 64 + d]; }
        else if (n < 2560)  { val = Wk[(size_t)k * 512 + (n - 2048)]; }
        else if (n < 3072)  { val = Wv[(size_t)k * 512 + (n - 2560)]; }
        else if (n < 3104)  { int h = n - 3072;           val = Wq[(size_t)k * 2080 + (h >> 2) * 260 + 256 + (h & 3)]; }
        tile[kr][nc] = val;
    }
    __syncthreads();
    for (int i = 0; i < 4; i++) {
        int idx = i * 256 + t;
        int nr = idx >> 5, kc = idx & 31;
        Wt[(size_t)(n0 + nr) * HDIM + (k0 + kc)] = f2bf(tile[kc][nr]);
    }
}

// ---------------- transpose-cast Wo -> bf16 (2048 x 2048) ----------------
__global__ void pack_wot_k(const float* __restrict__ Wo, unsigned short* __restrict__ Wt) {
    __shared__ float tile[32][33];
    int n0 = blockIdx.x * 32, k0 = blockIdx.y * 32;
    int t = threadIdx.x;
    for (int i = 0; i < 4; i++) {
        int idx = i * 256 + t;
        int kr = idx >> 5, nc = idx & 31;
        tile[kr][nc] = Wo[(size_t)(k0 + kr) * 2048 + (n0 + nc)];
    }
    __syncthreads();
    for (int i = 0; i < 4; i++) {
        int idx = i * 256 + t;
        int nr = idx >> 5, kc = idx & 31;
        Wt[(size_t)(n0 + nr) * 2048 + (k0 + kc)] = f2bf(tile[kc][nr]);
    }
}

// ---------------- NT GEMM, 64x128 tile, templated (R11) ----------------
// R7's proven pipeline (3-buf counted vmcnt(3) + static indices + chunk swizzle).
// NST = K-steps (64 QKV, 32 out-proj split-K). FUSE = QKV fused epilogue:
//   n-tiles 0..15 (Q) / 16..19 (K): in-register RMSNorm (4 sq + 4 shfl_xor over the
//   16-lane col group) + RoPE (pairs d,d+32 are lane-local j,j+2; shared angle) ->
//   write Qr/Kr bf16 directly. Tiles 20..23 (V): f32 -> QKVG for vt_k.
//   Tile 24 (gates): sigmoid -> gate[]. Deletes the norm_rope+gate kernels entirely.
template<int NST, bool FUSE>
__global__ __launch_bounds__(256) void gemm_nt64_k(const unsigned short* __restrict__ A,
                                                   const unsigned short* __restrict__ Bt,
                                                   float* __restrict__ C0,
                                                   float* __restrict__ C1,
                                                   int ldc, int mtiles, int ntiles,
                                                   unsigned short* __restrict__ Qr,
                                                   unsigned short* __restrict__ Kr,
                                                   float* __restrict__ gate,
                                                   const float* __restrict__ g_q,
                                                   const float* __restrict__ g_k) {
    const int K = 2048;
    __shared__ unsigned short As[3][64 * 32];
    __shared__ unsigned short Bs[3][128 * 32];
    int d = blockIdx.x;
    int nwg = gridDim.x;
    int cpx = nwg >> 3;
    int swz = (d & 7) * cpx + (d >> 3);
    int half = (swz >= ntiles) ? 1 : 0;
    int tile = swz - half * ntiles;
    int m0 = (tile % mtiles) * 64, n0 = (tile / mtiles) * 128;
    float* C = half ? C1 : C0;
    int koff = half * (NST * 32);
    int t = threadIdx.x;
    int w = t >> 6, l = t & 63;
    int wm = (w >> 1) * 32, wn = (w & 1) * 64;
    int lrow = l & 15, lc = l >> 4;
    int rsw = (lrow >> 1) & 3;
    int scol = ((l & 3) ^ ((l >> 3) & 3)) * 8;

    f32x4 acc[2][4];
    #pragma unroll
    for (int i = 0; i < 2; i++)
        #pragma unroll
        for (int j = 0; j < 4; j++)
            acc[i][j] = {0.f, 0.f, 0.f, 0.f};

    const unsigned short* ga = &A[(size_t)(m0 + w * 16 + (l >> 2)) * K + koff + scol];
    const unsigned short* gb = &Bt[(size_t)(n0 + w * 32 + (l >> 2)) * K + koff + scol];

#define STAGE_NT64(s, b) do { \
        gl_lds16(ga + (size_t)(s) * 32,                  &As[b][w * 512]); \
        gl_lds16(gb + (size_t)(s) * 32,                  &Bs[b][(w * 2 + 0) * 512]); \
        gl_lds16(gb + (size_t)(s) * 32 + 16 * (size_t)K, &Bs[b][(w * 2 + 1) * 512]); \
    } while (0)

#define GBODY(rb) do { \
        bh8 af[2], bb[4]; \
        _Pragma("unroll") \
        for (int i = 0; i < 2; i++) \
            af[i] = *(const bh8*)(&As[rb][(wm + i * 16 + lrow) * 32 + ((lc ^ rsw) * 8)]); \
        _Pragma("unroll") \
        for (int j = 0; j < 4; j++) \
            bb[j] = *(const bh8*)(&Bs[rb][(wn + j * 16 + lrow) * 32 + ((lc ^ rsw) * 8)]); \
        _Pragma("unroll") \
        for (int i = 0; i < 2; i++) \
            _Pragma("unroll") \
            for (int j = 0; j < 4; j++) \
                acc[i][j] = __builtin_amdgcn_mfma_f32_16x16x32_bf16(af[i], bb[j], acc[i][j], 0, 0, 0); \
    } while (0)

#define WB3 asm volatile("s_waitcnt vmcnt(3)\n\ts_barrier" ::: "memory")

    STAGE_NT64(0, 0);
    STAGE_NT64(1, 1);
    if constexpr (NST == 64) {
        for (int sb = 0; sb < 60; sb += 3) {
            WB3;
            STAGE_NT64(sb + 2, 2);
            GBODY(0);
            WB3;
            STAGE_NT64(sb + 3, 0);
            GBODY(1);
            WB3;
            STAGE_NT64(sb + 4, 1);
            GBODY(2);
        }
        WB3;
        STAGE_NT64(62, 2);
        GBODY(0);
        WB3;
        STAGE_NT64(63, 0);
        GBODY(1);
        WB3;
        GBODY(2);
        asm volatile("s_waitcnt vmcnt(0)\n\ts_barrier" ::: "memory");
        GBODY(0);
    } else {
        for (int sb = 0; sb < 30; sb += 3) {
            WB3;
            STAGE_NT64(sb + 2, 2);
            GBODY(0);
            WB3;
            STAGE_NT64(sb + 3, 0);
            GBODY(1);
            WB3;
            STAGE_NT64(sb + 4, 1);
            GBODY(2);
        }
        WB3;
        GBODY(0);
        asm volatile("s_waitcnt vmcnt(0)\n\ts_barrier" ::: "memory");
        GBODY(1);
    }
#undef WB3
#undef STAGE_NT64
#undef GBODY
    int col = l & 15, rbase = (l >> 4) * 4;
    if constexpr (FUSE) {
        int nt = n0 >> 7;
        if (nt < 20) {
            // ---- Q (nt<16) / K (16..19) head: fused RMSNorm + RoPE, write bf16
            bool isQ = nt < 16;
            int hd = ((n0 + wn) - (isQ ? 0 : 2048)) >> 6;
            unsigned short* dst = (isQ ? Qr : Kr) + (size_t)hd * SLEN * 64;
            const float* gv = isQ ? g_q : g_k;
            float g0 = gv[col], g1 = gv[col + 16], g2 = gv[col + 32], g3 = gv[col + 48];
            float invf0 = __expf(-(float)col * (0.03125f * 13.815510557964274f));
            float invf1 = __expf(-(float)(col + 16) * (0.03125f * 13.815510557964274f));
            float qs = isQ ? QSCALE : 1.0f;
            #pragma unroll
            for (int i = 0; i < 2; i++)
                #pragma unroll
                for (int r = 0; r < 4; r++) {
                    int s = m0 + wm + i * 16 + rbase + r;
                    float x0 = acc[i][0][r], x1 = acc[i][1][r];
                    float x2 = acc[i][2][r], x3 = acc[i][3][r];
                    float sq = x0 * x0 + x1 * x1 + x2 * x2 + x3 * x3;
                    sq += __shfl_xor(sq, 1);
                    sq += __shfl_xor(sq, 2);
                    sq += __shfl_xor(sq, 4);
                    sq += __shfl_xor(sq, 8);
                    float inv = rsqrtf(sq * (1.f / 64.f) + 1e-6f);
                    float xn0 = x0 * inv * g0, xn1 = x1 * inv * g1;
                    float xn2 = x2 * inv * g2, xn3 = x3 * inv * g3;
                    float a0 = (float)s * invf0, a1 = (float)s * invf1;
                    float c0 = cosf(a0), sn0 = sinf(a0);
                    float c1 = cosf(a1), sn1 = sinf(a1);
                    unsigned short* dr = dst + (size_t)s * 64;
                    dr[col]      = f2bf((xn0 * c0 - xn2 * sn0) * qs);   // d<32: -x[d+32]*sin
                    dr[col + 16] = f2bf((xn1 * c1 - xn3 * sn1) * qs);
                    dr[col + 32] = f2bf((xn2 * c0 + xn0 * sn0) * qs);   // d>=32: +x[d-32]*sin
                    dr[col + 48] = f2bf((xn3 * c1 + xn1 * sn1) * qs);
                }
        } else if (nt < 24) {
            // ---- V: plain f32 store to QKVG (consumed by vt_k)
            for (int i = 0; i < 2; i++)
                for (int j = 0; j < 4; j++)
                    #pragma unroll
                    for (int r = 0; r < 4; r++)
                        C[(size_t)(m0 + wm + i * 16 + rbase + r) * ldc + (n0 + wn + j * 16 + col)] = acc[i][j][r];
        } else {
            // ---- gates: cols 3072..3103 (wn==0, j<2): sigmoid -> gate[s*32+h]
            if (wn == 0) {
                #pragma unroll
                for (int i = 0; i < 2; i++)
                    #pragma unroll
                    for (int j = 0; j < 2; j++)
                        #pragma unroll
                        for (int r = 0; r < 4; r++) {
                            int s = m0 + wm + i * 16 + rbase + r;
                            int h = j * 16 + col;
                            gate[s * 32 + h] = 1.f / (1.f + __expf(-acc[i][j][r]));
                        }
            }
        }
    } else {
        for (int i = 0; i < 2; i++)
            for (int j = 0; j < 4; j++)
                #pragma unroll
                for (int r = 0; r < 4; r++)
                    C[(size_t)(m0 + wm + i * 16 + rbase + r) * ldc + (n0 + wn + j * 16 + col)] = acc[i][j][r];
    }
}

// ---------------- out-proj split-K reduce: out = P0 + P1 (2048^2 f32) ----------------
__global__ void addf4_k(const float* __restrict__ a, const float* __restrict__ b,
                        float* __restrict__ o) {
    int i = (blockIdx.x * 256 + threadIdx.x) * 4;
    float4 x = *(const float4*)(a + i);
    float4 y = *(const float4*)(b + i);
    float4 r; r.x = x.x + y.x; r.y = x.y + y.y; r.z = x.z + y.z; r.w = x.w + y.w;
    *(float4*)(o + i) = r;
}

// ---------------- V transpose + key-permute: QKVG[s][2560+hh*64+d] -> Vt[hh][d][perm(s)] ----
__global__ void vt_k(const float* __restrict__ QKVG, unsigned short* __restrict__ Vt) {
    __shared__ float tile[64][65];
    int s0 = blockIdx.x * 64, hh = blockIdx.y;
    int t = threadIdx.x;
    #pragma unroll
    for (int i = 0; i < 4; i++) {
        int idx = i * 256 + t;
        int sr = idx >> 4, c4 = (idx & 15) * 4;
        float4 f = *(const float4*)(&QKVG[(size_t)(s0 + sr) * NPAD + 2560 + hh * 64 + c4]);
        tile[sr][c4] = f.x; tile[sr][c4 + 1] = f.y; tile[sr][c4 + 2] = f.z; tile[sr][c4 + 3] = f.w;
    }
    __syncthreads();
    #pragma unroll
    for (int i = 0; i < 4; i++) {
        int idx = i * 256 + t;
        int dr = idx >> 4, c4 = (idx & 15) * 4;
        int hb = c4 >> 5, f = (c4 >> 4) & 1, g = (c4 >> 2) & 3;
        int p = (hb * 4 + g) * 8 + f * 4;
        ushort4 o;
        o.x = f2bf(tile[c4][dr]); o.y = f2bf(tile[c4 + 1][dr]);
        o.z = f2bf(tile[c4 + 2][dr]); o.w = f2bf(tile[c4 + 3][dr]);
        *(ushort4*)(&Vt[((size_t)hh * 64 + dr) * SLEN + s0 + p]) = o;
    }
}

// ---------------- causal GQA flash attention + gate (R4 structure, unchanged) ----------------
__global__ __launch_bounds__(256) void attn_k(const unsigned short* __restrict__ Qr,
                                              const unsigned short* __restrict__ Kr,
                                              const unsigned short* __restrict__ Vt,
                                              const float* __restrict__ gate,
                                              unsigned short* __restrict__ attn) {
    __shared__ unsigned short Kls[3][64 * 64];
    __shared__ unsigned short Vls[3][64 * 64];
    int d = blockIdx.x;
    int kvh = d & 7;
    int h = kvh * 4 + ((d >> 3) & 3);
    int qt = 31 - (d >> 5);          // big-first: span-32 blocks dispatch first
    int t = threadIdx.x, w = t >> 6, l = t & 63;
    int ql = l & 15, g = l >> 4;
    const float NEGINF = -__builtin_inff();

    const unsigned short* Kh = Kr + (size_t)kvh * SLEN * 64;
    const unsigned short* Vh = Vt + (size_t)kvh * 64 * SLEN;
    const unsigned short* Qh = Qr + (size_t)h * SLEN * 64;
    int lk = g * 8;
    int r8 = l >> 3, c8 = l & 7;
    int cs = 8 * (c8 ^ r8);          // pre-swizzled source col (shorts)
    int R0 = w * 16, R1 = w * 16 + 8;
    int rdswz = (ql & 7) << 4;       // read-side XOR swizzle (bytes)

    int q0 = qt * 64;
    int qrow = q0 + w * 16 + ql;

    bh8 qa0 = *(const bh8*)(Qh + (size_t)qrow * 64 + lk);
    bh8 qa1 = *(const bh8*)(Qh + (size_t)qrow * 64 + 32 + lk);

    f32x4 o[4];
    #pragma unroll
    for (int i = 0; i < 4; i++) o[i] = {0.f, 0.f, 0.f, 0.f};
    float m2 = NEGINF, lsum = 0.f;

    int ntiles = qt + 1;
    {
        gl_lds16(&Kh[(size_t)(0 + R0 + r8) * 64 + cs], &Kls[0][R0 * 64]);
        gl_lds16(&Kh[(size_t)(0 + R1 + r8) * 64 + cs], &Kls[0][R1 * 64]);
        gl_lds16(&Vh[(size_t)(R0 + r8) * SLEN + 0 + cs], &Vls[0][R0 * 64]);
        gl_lds16(&Vh[(size_t)(R1 + r8) * SLEN + 0 + cs], &Vls[0][R1 * 64]);
    }
    if (ntiles > 1) {
        gl_lds16(&Kh[(size_t)(64 + R0 + r8) * 64 + cs], &Kls[1][R0 * 64]);
        gl_lds16(&Kh[(size_t)(64 + R1 + r8) * 64 + cs], &Kls[1][R1 * 64]);
        gl_lds16(&Vh[(size_t)(R0 + r8) * SLEN + 64 + cs], &Vls[1][R0 * 64]);
        gl_lds16(&Vh[(size_t)(R1 + r8) * SLEN + 64 + cs], &Vls[1][R1 * 64]);
    }
    int rd = 0, wr = 2;

    for (int ti = 0; ti < ntiles; ti++) {
        if (ti + 1 < ntiles) asm volatile("s_waitcnt vmcnt(4)\n\ts_barrier" ::: "memory");
        else                 asm volatile("s_waitcnt vmcnt(0)\n\ts_barrier" ::: "memory");
        if (ti + 2 < ntiles) {
            int kv1 = (ti + 2) * 64;
            gl_lds16(&Kh[(size_t)(kv1 + R0 + r8) * 64 + cs], &Kls[wr][R0 * 64]);
            gl_lds16(&Kh[(size_t)(kv1 + R1 + r8) * 64 + cs], &Kls[wr][R1 * 64]);
            gl_lds16(&Vh[(size_t)(R0 + r8) * SLEN + kv1 + cs], &Vls[wr][R0 * 64]);
            gl_lds16(&Vh[(size_t)(R1 + r8) * SLEN + kv1 + cs], &Vls[wr][R1 * 64]);
        }
        const unsigned short* Kb = &Kls[rd][0];
        const unsigned short* Vb = &Vls[rd][0];
        int kv0 = ti * 64;
        f32x4 sct[4];
        __builtin_amdgcn_s_setprio(1);
        #pragma unroll
        for (int nt = 0; nt < 4; nt++) {
            int rb = (nt * 16 + ql) * 128;
            bh8 kb0 = *(const bh8*)(&Kb[(rb + ((g * 16) ^ rdswz)) >> 1]);
            bh8 kb1 = *(const bh8*)(&Kb[(rb + ((64 + g * 16) ^ rdswz)) >> 1]);
            f32x4 a = {0.f, 0.f, 0.f, 0.f};
            a = __builtin_amdgcn_mfma_f32_16x16x32_bf16(kb0, qa0, a, 0, 0, 0);
            a = __builtin_amdgcn_mfma_f32_16x16x32_bf16(kb1, qa1, a, 0, 0, 0);
            sct[nt] = a;
        }
        __builtin_amdgcn_s_setprio(0);
        if (ti == qt) {
            #pragma unroll
            for (int nt = 0; nt < 4; nt++)
                #pragma unroll
                for (int j = 0; j < 4; j++) {
                    int key = kv0 + nt * 16 + 4 * g + j;
                    if (key > qrow) sct[nt][j] = NEGINF;
                }
        }
        float mt0 = fmaxf(fmaxf(sct[0][0], sct[0][1]), fmaxf(sct[0][2], sct[0][3]));
        float mt1 = fmaxf(fmaxf(sct[1][0], sct[1][1]), fmaxf(sct[1][2], sct[1][3]));
        float mt2 = fmaxf(fmaxf(sct[2][0], sct[2][1]), fmaxf(sct[2][2], sct[2][3]));
        float mt3 = fmaxf(fmaxf(sct[3][0], sct[3][1]), fmaxf(sct[3][2], sct[3][3]));
        float mt = fmaxf(fmaxf(mt0, mt1), fmaxf(mt2, mt3));
        mt = fmaxf(mt, __shfl_xor(mt, 16));
        mt = fmaxf(mt, __shfl_xor(mt, 32));
        if (!__all(mt - m2 <= 8.f)) {
            float mnew = fmaxf(m2, mt);
            float resc = __builtin_amdgcn_exp2f(m2 - mnew);
            m2 = mnew;
            lsum *= resc;
            float rf[4];
            #pragma unroll
            for (int j = 0; j < 4; j++) rf[j] = __shfl(resc, 4 * g + j);
            #pragma unroll
            for (int nt = 0; nt < 4; nt++) {
                f32x4 oo = o[nt];
                #pragma unroll
                for (int j = 0; j < 4; j++) oo[j] *= rf[j];
                o[nt] = oo;
            }
        }
        float ps = 0.f;
        #pragma unroll
        for (int nt = 0; nt < 4; nt++)
            #pragma unroll
            for (int j = 0; j < 4; j++) {
                float p = __builtin_amdgcn_exp2f(sct[nt][j] - m2);
                sct[nt][j] = p;
                ps += p;
            }
        ps += __shfl_xor(ps, 16);
        ps += __shfl_xor(ps, 32);
        lsum += ps;
        union { unsigned int u[4]; bh8 v; } pa0, pa1;
        pa0.u[0] = cvtpk_bf16(sct[0][0], sct[0][1]);
        pa0.u[1] = cvtpk_bf16(sct[0][2], sct[0][3]);
        pa0.u[2] = cvtpk_bf16(sct[1][0], sct[1][1]);
        pa0.u[3] = cvtpk_bf16(sct[1][2], sct[1][3]);
        pa1.u[0] = cvtpk_bf16(sct[2][0], sct[2][1]);
        pa1.u[1] = cvtpk_bf16(sct[2][2], sct[2][3]);
        pa1.u[2] = cvtpk_bf16(sct[3][0], sct[3][1]);
        pa1.u[3] = cvtpk_bf16(sct[3][2], sct[3][3]);
        __builtin_amdgcn_s_setprio(1);
        #pragma unroll
        for (int nt = 0; nt < 4; nt++) {
            int rb = (nt * 16 + ql) * 128;
            bh8 vb0 = *(const bh8*)(&Vb[(rb + ((g * 16) ^ rdswz)) >> 1]);
            bh8 vb1 = *(const bh8*)(&Vb[(rb + ((64 + g * 16) ^ rdswz)) >> 1]);
            o[nt] = __builtin_amdgcn_mfma_f32_16x16x32_bf16(pa0.v, vb0, o[nt], 0, 0, 0);
            o[nt] = __builtin_amdgcn_mfma_f32_16x16x32_bf16(pa1.v, vb1, o[nt], 0, 0, 0);
        }
        __builtin_amdgcn_s_setprio(0);
        rd = (rd == 2) ? 0 : rd + 1;
        wr = (wr == 2) ? 0 : wr + 1;
    }

    float gf[4];
    #pragma unroll
    for (int j = 0; j < 4; j++) {
        float ls = __shfl(lsum, 4 * g + j);
        int row = q0 + w * 16 + 4 * g + j;
        gf[j] = gate[row * 32 + h] / ls;
    }
    #pragma unroll
    for (int j = 0; j < 4; j++) {
        int row = q0 + w * 16 + 4 * g + j;
        #pragma unroll
        for (int nt = 0; nt < 4; nt++)
            attn[(size_t)row * 2048 + h * 64 + nt * 16 + ql] = f2bf(o[nt][j] * gf[j]);
    }
}

extern "C" void kernel_launch(void* const* d_in, const int* in_sizes, int n_in,
                              void* d_out, int out_size, void* d_ws, size_t ws_size,
                              hipStream_t stream) {
    const float* hidden = (const float*)d_in[0];
    const float* Wq = (const float*)d_in[1];
    const float* Wk = (const float*)d_in[2];
    const float* Wv = (const float*)d_in[3];
    const float* Wo = (const float*)d_in[4];
    const float* gq = (const float*)d_in[5];
    const float* gk = (const float*)d_in[6];
    float* out = (float*)d_out;
    char* ws = (char*)d_ws;

    unsigned short* X     = (unsigned short*)(ws + 0);         //  8388608 B
    unsigned short* Wt    = (unsigned short*)(ws + 8388608);   // 13107200 B
    float*          QKVG  = (float*)(ws + 21495808);           // 26214400 B (V cols only; reused as P0)
    unsigned short* Qr    = (unsigned short*)(ws + 47710208);  //  8388608 B
    unsigned short* Kr    = (unsigned short*)(ws + 56098816);  //  2097152 B
    unsigned short* Vt    = (unsigned short*)(ws + 58195968);  //  2097152 B
    float*          gate  = (float*)(ws + 60293120);           //   262144 B
    unsigned short* attnb = (unsigned short*)(ws + 60555264);  //  8388608 B
    unsigned short* Wot   = (unsigned short*)(ws + 68943872);  //  8388608 B
    float*          P1    = (float*)(ws + 77332480);           // 16777216 B (out-proj split-K partial)
    float*          P0    = QKVG;                              // dead after vt_k

    cast_x_k<<<dim3(4096), dim3(256), 0, stream>>>(hidden, X, SLEN * HDIM);
    pack_wt_k<<<dim3(100, 64), dim3(256), 0, stream>>>(Wq, Wk, Wv, Wt);
    pack_wot_k<<<dim3(64, 64), dim3(256), 0, stream>>>(Wo, Wot);
    gemm_nt64_k<64, true><<<dim3(800), dim3(256), 0, stream>>>(X, Wt, QKVG, QKVG, NPAD, 32, 800,
                                                               Qr, Kr, gate, gq, gk);
    vt_k<<<dim3(32, 8), dim3(256), 0, stream>>>(QKVG, Vt);
    attn_k<<<dim3(1024), dim3(256), 0, stream>>>(Qr, Kr, Vt, gate, attnb);
    gemm_nt64_k<32, false><<<dim3(1024), dim3(256), 0, stream>>>(attnb, Wot, P0, P1, 2048, 32, 512,
                                                                 nullptr, nullptr, nullptr, nullptr, nullptr);
    addf4_k<<<dim3(4096), dim3(256), 0, stream>>>(P0, P1, out);
}